// Round 8
// baseline (429.703 us; speedup 1.0000x reference)
//
#include <hip/hip_runtime.h>
#include <stdint.h>
#include <math.h>

#define SEQ 4096
#define DM  1024
#define NH  16
#define DH  64
#define LOG2E 1.44269504088896341f

typedef short bf16x8 __attribute__((ext_vector_type(8)));
typedef short bf16x4 __attribute__((ext_vector_type(4)));
typedef float f32x4  __attribute__((ext_vector_type(4)));
typedef uint32_t u32x4 __attribute__((ext_vector_type(4)));

typedef const __attribute__((address_space(1))) short* gptr_t;
typedef __attribute__((address_space(3))) short* lptr_t;

__device__ __forceinline__ short f2bf(float f) {
    union { float f; uint32_t u; } x; x.f = f;
    uint32_t r = (x.u + 0x7fffu + ((x.u >> 16) & 1u)) >> 16;
    return (short)r;
}
// pack two f32 -> dword of two truncated bf16 (lo in low half) — plain bit
// ops, fully schedulable (inline-asm variants measured -35%; m240)
__device__ __forceinline__ uint32_t pkbf(float lo, float hi) {
    union { float f; uint32_t u; } a, b; a.f = lo; b.f = hi;
    return (a.u >> 16) | (b.u & 0xffff0000u);
}

__device__ __forceinline__ void load_lds16(const short* g, const short* l) {
    __builtin_amdgcn_global_load_lds((gptr_t)(uintptr_t)g,
                                     (lptr_t)(uint32_t)(uintptr_t)l, 16, 0, 0);
}

// raw workgroup barrier with compiler memory fence (no vmcnt auto-drain)
__device__ __forceinline__ void wgbar() {
    asm volatile("" ::: "memory");
    __builtin_amdgcn_s_barrier();
    asm volatile("" ::: "memory");
}
#define WAITVM(n) asm volatile("s_waitcnt vmcnt(" #n ")" ::: "memory")
#define WAITLGKM(n) do { asm volatile("s_waitcnt lgkmcnt(" #n ")" ::: "memory"); \
                         __builtin_amdgcn_sched_barrier(0); } while (0)
#define DSR(d, a, o) asm volatile("ds_read_b128 %0, %1 offset:" o : "=v"(d) : "v"(a))

// ---- fused prep: blocks [0,2048) convert x fp32->bf16; blocks [2048,2816)
//      transpose w [1024][3072] -> wtb [3072][1024] bf16, Q cols pre-scaled.
//      Block 0 also zeroes the 512 split-K pair flags (runs before attn). ----
__global__ __launch_bounds__(256) void cvt_fused(const float* __restrict__ x,
                                                 const float* __restrict__ w,
                                                 short* __restrict__ xb,
                                                 short* __restrict__ wtb,
                                                 int* __restrict__ flags) {
    __shared__ float T[64][69];
    const int b = blockIdx.x;
    if (b == 0) {
        flags[threadIdx.x] = 0;
        flags[256 + threadIdx.x] = 0;
    }
    if (b < 2048) {
        const int i = (b * 256 + threadIdx.x) * 8;
        float4 a0 = ((const float4*)(x + i))[0];
        float4 a1 = ((const float4*)(x + i))[1];
        bf16x8 p;
        p[0]=f2bf(a0.x); p[1]=f2bf(a0.y); p[2]=f2bf(a0.z); p[3]=f2bf(a0.w);
        p[4]=f2bf(a1.x); p[5]=f2bf(a1.y); p[6]=f2bf(a1.z); p[7]=f2bf(a1.w);
        *(bf16x8*)(xb + i) = p;
        return;
    }
    const int bb = b - 2048;
    const int n0 = (bb % 48) * 64, k0 = (bb / 48) * 64;
    const int t = threadIdx.x;
    {
        const int kr = t >> 4, nc = (t & 15) * 4;
        #pragma unroll
        for (int i = 0; i < 4; ++i) {
            float4 v = *(const float4*)(w + (size_t)(k0 + kr + i * 16) * 3072 + n0 + nc);
            T[kr + i * 16][nc + 0] = v.x; T[kr + i * 16][nc + 1] = v.y;
            T[kr + i * 16][nc + 2] = v.z; T[kr + i * 16][nc + 3] = v.w;
        }
    }
    __syncthreads();
    const int nr = t >> 4, kc = (t & 15) * 4;
    #pragma unroll
    for (int i = 0; i < 4; ++i) {
        const int n = n0 + nr + i * 16;
        const float sc = (n >= 1024 && n < 2048) ? (LOG2E / 32.0f) : 1.0f;
        short4 o;
        o.x = f2bf(T[kc + 0][nr + i * 16] * sc);
        o.y = f2bf(T[kc + 1][nr + i * 16] * sc);
        o.z = f2bf(T[kc + 2][nr + i * 16] * sc);
        o.w = f2bf(T[kc + 3][nr + i * 16] * sc);
        *(short4*)(wtb + (size_t)n * 1024 + k0 + kc) = o;
    }
}

// ---- QKV GEMM v7 (proven): 128x128 tile, BK=64, distance-2 prefetch,
//      counted vmcnt(8), raw barriers, XOR-8 swizzled LDS, asm ds_read.
//      (Asm scheduling pinning is SAFE here: loop is ~pure MFMA, unlike
//      attn's VALU-heavy loop where the same recipe regressed 60%.) ----
__global__ __launch_bounds__(256, 2) void qkv_gemm(const short* __restrict__ xb,
                                                   const short* __restrict__ wtb,
                                                   short* __restrict__ kq,
                                                   short* __restrict__ vt) {
    __shared__ short As[2][8192];
    __shared__ short Bs[2][8192];
    const int col0 = blockIdx.y * 128, row0 = blockIdx.x * 128;
    const int tid = threadIdx.x, w = tid >> 6, lane = tid & 63;
    const int lmod = lane & 15, ldiv = lane >> 4;
    const int wr = (w >> 1) * 64, wc = (w & 1) * 64;

    const int srow = w * 32 + (lane >> 3);
    const int slc  = (lane & 7) ^ ((lane >> 3) & 7);
    const short* gA = xb  + (size_t)(row0 + srow) * 1024 + slc * 8;
    const short* gB = wtb + (size_t)(col0 + srow) * 1024 + slc * 8;
    short* lA = &As[0][0] + w * 2048;
    short* lB = &Bs[0][0] + w * 2048;

    const uint32_t asb = (uint32_t)(uintptr_t)&As[0][0];
    const uint32_t bsb = (uint32_t)(uintptr_t)&Bs[0][0];
    const int xorm = lmod & 7;
    const int rdA = (wr + lmod) * 128 + ((ldiv ^ xorm) << 4);
    const int rdB = (wc + lmod) * 128 + ((ldiv ^ xorm) << 4);

    f32x4 acc[4][4] = {};

    auto stage = [&](int kt, int p) {
        const short* ga = gA + kt * 64;
        const short* gb = gB + kt * 64;
        short* la = lA + p * 8192;
        short* lb = lB + p * 8192;
        #pragma unroll
        for (int q = 0; q < 4; ++q) {
            load_lds16(ga + q * 8192, la + q * 512);
            load_lds16(gb + q * 8192, lb + q * 512);
        }
    };

    stage(0, 0);
    stage(1, 1);
    WAITVM(8);
    wgbar();

    for (int t = 0; t < 16; ++t) {
        const int poff = (t & 1) << 14;
        const int aA0 = (int)asb + poff + rdA, aA1 = aA0 ^ 64;
        const int bA0 = (int)bsb + poff + rdB, bA1 = bA0 ^ 64;
        bf16x8 a0[4], a1[4], b0[4], b1[4];
        DSR(a0[0], aA0, "0");    DSR(a0[1], aA0, "2048");
        DSR(a0[2], aA0, "4096"); DSR(a0[3], aA0, "6144");
        DSR(b0[0], bA0, "0");    DSR(b0[1], bA0, "2048");
        DSR(b0[2], bA0, "4096"); DSR(b0[3], bA0, "6144");
        DSR(a1[0], aA1, "0");    DSR(a1[1], aA1, "2048");
        DSR(a1[2], aA1, "4096"); DSR(a1[3], aA1, "6144");
        DSR(b1[0], bA1, "0");    DSR(b1[1], bA1, "2048");
        DSR(b1[2], bA1, "4096"); DSR(b1[3], bA1, "6144");
        WAITLGKM(8);
        #pragma unroll
        for (int i = 0; i < 4; ++i)
            #pragma unroll
            for (int j = 0; j < 4; ++j)
                acc[i][j] = __builtin_amdgcn_mfma_f32_16x16x32_bf16(a0[i], b0[j], acc[i][j], 0, 0, 0);
        WAITLGKM(0);
        #pragma unroll
        for (int i = 0; i < 4; ++i)
            #pragma unroll
            for (int j = 0; j < 4; ++j)
                acc[i][j] = __builtin_amdgcn_mfma_f32_16x16x32_bf16(a1[i], b1[j], acc[i][j], 0, 0, 0);

        wgbar();
        if (t + 2 < 16) {
            stage(t + 2, t & 1);
            WAITVM(8);
            wgbar();
        } else if (t + 1 < 16) {
            WAITVM(0);
            wgbar();
        }
    }

    if (col0 < 2048) {
        #pragma unroll
        for (int i = 0; i < 4; ++i)
            #pragma unroll
            for (int j = 0; j < 4; ++j)
                #pragma unroll
                for (int r = 0; r < 4; ++r)
                    kq[(size_t)(row0 + wr + i * 16 + ldiv * 4 + r) * 2048
                       + col0 + wc + j * 16 + lmod] = f2bf(acc[i][j][r]);
    } else {
        #pragma unroll
        for (int i = 0; i < 4; ++i) {
            const int ig = row0 + wr + i * 16 + ldiv * 4;
            const int kk = ig & 63;
            // tau: 32a+16b+4c -> 32a+8c+4b
            const int kkp = (kk & 32) | ((kk & 12) << 1) | ((kk & 16) >> 2);
            const int igp = (ig & ~63) | kkp;
            #pragma unroll
            for (int j = 0; j < 4; ++j) {
                const int cg = col0 + wc + j * 16 + lmod - 2048;
                const int h = cg >> 6, d = cg & 63;
                bf16x4 p;
                p[0]=f2bf(acc[i][j][0]); p[1]=f2bf(acc[i][j][1]);
                p[2]=f2bf(acc[i][j][2]); p[3]=f2bf(acc[i][j][3]);
                *(bf16x4*)(vt + (size_t)(h * 64 + d) * SEQ + igp) = p;
            }
        }
    }
}

// ---- flash attention, split-K 2-way.
//  v9 = v6 loop EXACTLY (single-buffer LDS, 2-barrier staging, zero inline
//  asm in the compute loop — every asm variant regressed 55-60%: v4/v5/v8)
//  + fused combine epilogue: both blocks of a (qt,h) pair write partials;
//  the second arrival (atomic flag) merges its own registers with the
//  partner's partial from L2 and writes the final output. ----
__global__ __launch_bounds__(256, 4) void attn(const short* __restrict__ kq,
                                               const short* __restrict__ vt,
                                               float* __restrict__ o0,
                                               float* __restrict__ o1,
                                               float* __restrict__ ls0,
                                               float* __restrict__ ls1,
                                               int* __restrict__ flags) {
    __shared__ short Ks[64 * 64];
    __shared__ short Vs[64 * 64];

    // band-interleaved decode: per-CU resident set sums to 66 units
    const int b = blockIdx.x;
    const int band = b >> 8, pos = b & 255, g = pos >> 5;
    const int qt = (band & 1) ? (24 - band * 8 + g) : (31 - band * 8 - g);
    const int h = (pos >> 1) & 15, s = pos & 1;

    const int tid = threadIdx.x, w = tid >> 6, lane = tid & 63;
    const int lmod = lane & 15, ldiv = lane >> 4;
    const float slope2 = exp2f(-0.5f * (float)(h + 1)) * LOG2E;

    // staging: wave w stages rows w*16..w*16+15 of both K and V tiles.
    const int sr0 = w * 16 + (lane >> 3), sr1 = sr0 + 8;
    const int sc0 = (lane & 7) ^ (sr0 & 7), sc1 = (lane & 7) ^ (sr1 & 7);

    const int xorm = lmod & 7;                 // read-side swizzle
    const int cxs0 = (ldiv ^ xorm) * 8;        // phys short offset, chunk ldiv
    const int cxs1 = ((4 + ldiv) ^ xorm) * 8;  // phys short offset, chunk 4+ldiv

    const int rowbase = qt * 128 + w * 32;

    // Q fragments (2 m-blocks x 2 d-chunks) — the MFMA B operand
    bf16x8 qf[2][2];
    #pragma unroll
    for (int m = 0; m < 2; ++m) {
        const short* qp = kq + (size_t)(rowbase + m * 16 + lmod) * 2048 + 1024 + h * 64;
        qf[m][0] = *(const bf16x8*)(qp + ldiv * 8);
        qf[m][1] = *(const bf16x8*)(qp + 32 + ldiv * 8);
    }
    // swapped layout: lane holds S[k = kt*64 + nt*16 + 4*ldiv + r][q = lmod]
    int db2[2];
    float pre[2][4];
    #pragma unroll
    for (int m = 0; m < 2; ++m) {
        db2[m] = 4 * ldiv - (rowbase + m * 16 + lmod);
        #pragma unroll
        for (int r = 0; r < 4; ++r) pre[m][r] = slope2 * (float)(db2[m] + r);
    }

    f32x4 O[2][4] = {};
    float lsum[2] = {};
    const int kt0 = s ? (qt + 1) : 0;
    const int kt1 = s ? (2 * qt + 2) : (qt + 1);

    for (int kt = kt0; kt < kt1; ++kt) {
        __syncthreads();   // prev compute done reading Ks/Vs
        {
            const short* kb = kq + (size_t)(kt * 64) * 2048 + h * 64;
            load_lds16(kb + (size_t)sr0 * 2048 + sc0 * 8, Ks + (w * 16) * 64);
            load_lds16(kb + (size_t)sr1 * 2048 + sc1 * 8, Ks + (w * 16 + 8) * 64);
            const short* vb = vt + (size_t)(h * 64) * SEQ + kt * 64;
            load_lds16(vb + (size_t)sr0 * SEQ + sc0 * 8, Vs + (w * 16) * 64);
            load_lds16(vb + (size_t)sr1 * SEQ + sc1 * 8, Vs + (w * 16 + 8) * 64);
        }
        __syncthreads();   // vmcnt drained -> LDS ready

        const bool diag = (kt >= 2 * qt);
        const int dt = kt * 64;
        const float cb = slope2 * (float)dt;

        #pragma unroll
        for (int ks = 0; ks < 2; ++ks) {       // 32-key chunk for PV
            u32x4 pk0, pk1;
            #pragma unroll
            for (int j1 = 0; j1 < 2; ++j1) {   // K 16-row block nt = 2ks+j1
                const int nt = ks * 2 + j1;
                const float cn = cb + slope2 * (float)(nt * 16);
                f32x4 s0, s1;
                #pragma unroll
                for (int r = 0; r < 4; ++r) { s0[r] = pre[0][r] + cn; s1[r] = pre[1][r] + cn; }
                const short* krow = Ks + (nt * 16 + lmod) * 64;
                const bf16x8 kf0 = *(const bf16x8*)(krow + cxs0);
                const bf16x8 kf1 = *(const bf16x8*)(krow + cxs1);
                s0 = __builtin_amdgcn_mfma_f32_16x16x32_bf16(kf0, qf[0][0], s0, 0, 0, 0);
                s0 = __builtin_amdgcn_mfma_f32_16x16x32_bf16(kf1, qf[0][1], s0, 0, 0, 0);
                s1 = __builtin_amdgcn_mfma_f32_16x16x32_bf16(kf0, qf[1][0], s1, 0, 0, 0);
                s1 = __builtin_amdgcn_mfma_f32_16x16x32_bf16(kf1, qf[1][1], s1, 0, 0, 0);

                float p0[4], p1[4];
                if (diag) {
                    #pragma unroll
                    for (int r = 0; r < 4; ++r) {
                        float v0 = s0[r], v1 = s1[r];
                        if (dt + nt * 16 + r + db2[0] > 0) v0 = -1e30f;
                        if (dt + nt * 16 + r + db2[1] > 0) v1 = -1e30f;
                        p0[r] = __builtin_amdgcn_exp2f(v0);
                        p1[r] = __builtin_amdgcn_exp2f(v1);
                    }
                } else {
                    #pragma unroll
                    for (int r = 0; r < 4; ++r) {
                        p0[r] = __builtin_amdgcn_exp2f(s0[r]);
                        p1[r] = __builtin_amdgcn_exp2f(s1[r]);
                    }
                }
                lsum[0] += (p0[0] + p0[1]) + (p0[2] + p0[3]);
                lsum[1] += (p1[0] + p1[1]) + (p1[2] + p1[3]);
                pk0[j1 * 2]     = pkbf(p0[0], p0[1]);
                pk0[j1 * 2 + 1] = pkbf(p0[2], p0[3]);
                pk1[j1 * 2]     = pkbf(p1[0], p1[1]);
                pk1[j1 * 2 + 1] = pkbf(p1[2], p1[3]);
            }
            const bf16x8 pa0 = __builtin_bit_cast(bf16x8, pk0);
            const bf16x8 pa1 = __builtin_bit_cast(bf16x8, pk1);
            const int cxo = ks ? cxs1 : cxs0;
            #pragma unroll
            for (int nt2 = 0; nt2 < 4; ++nt2) {
                const bf16x8 vf = *(const bf16x8*)(Vs + (nt2 * 16 + lmod) * 64 + cxo);
                O[0][nt2] = __builtin_amdgcn_mfma_f32_16x16x32_bf16(pa0, vf, O[0][nt2], 0, 0, 0);
                O[1][nt2] = __builtin_amdgcn_mfma_f32_16x16x32_bf16(pa1, vf, O[1][nt2], 0, 0, 0);
            }
        }
    }

    // row sums: lane holds partial for q = lmod; reduce across ldiv groups
    #pragma unroll
    for (int m = 0; m < 2; ++m) {
        float v = lsum[m];
        v += __shfl_xor(v, 16);
        v += __shfl_xor(v, 32);
        lsum[m] = v;
    }

    float* ob = s ? o1 : o0;
    float* lb = s ? ls1 : ls0;
    #pragma unroll
    for (int m = 0; m < 2; ++m) {
        const int i0 = rowbase + m * 16 + ldiv * 4;
        #pragma unroll
        for (int nt2 = 0; nt2 < 4; ++nt2)
            #pragma unroll
            for (int r = 0; r < 4; ++r)
                ob[(size_t)(i0 + r) * DM + h * 64 + nt2 * 16 + lmod] = O[m][nt2][r];
    }
    if (ldiv == 0) {
        #pragma unroll
        for (int m = 0; m < 2; ++m)
            lb[h * SEQ + rowbase + m * 16 + lmod] = lsum[m];
    }

    // ---- fused combine: second arrival of the (qt,h) pair merges halves ----
    __threadfence();
    __syncthreads();
    __shared__ int finsh;
    if (tid == 0) finsh = atomicAdd(&flags[qt * NH + h], 1);
    __syncthreads();
    if (finsh == 0) return;
    __threadfence();   // acquire partner's published partial

    const float* pb  = s ? o0 : o1;    // partner partial O
    const float* plb = s ? ls0 : ls1;  // partner lsum
    const float* olb = s ? ls1 : ls0;  // own lsum (published above)
    #pragma unroll
    for (int m = 0; m < 2; ++m) {
        const int i0 = rowbase + m * 16 + ldiv * 4;
        float rc[4];
        #pragma unroll
        for (int r = 0; r < 4; ++r)
            rc[r] = 1.0f / (olb[h * SEQ + i0 + r] + plb[h * SEQ + i0 + r]);
        #pragma unroll
        for (int nt2 = 0; nt2 < 4; ++nt2)
            #pragma unroll
            for (int r = 0; r < 4; ++r) {
                const size_t idx = (size_t)(i0 + r) * DM + h * 64 + nt2 * 16 + lmod;
                o0[idx] = (O[m][nt2][r] + pb[idx]) * rc[r];
            }
    }
}

extern "C" void kernel_launch(void* const* d_in, const int* in_sizes, int n_in,
                              void* d_out, int out_size, void* d_ws, size_t ws_size,
                              hipStream_t stream) {
    const float* x = (const float*)d_in[0];   // [1,4096,1024] fp32
    const float* w = (const float*)d_in[1];   // [1024,3072] fp32
    float* out = (float*)d_out;

    char* ws = (char*)d_ws;
    short* kq    = (short*)(ws);                        // 16 MB: K|Q [4096][2048]
    short* vt    = (short*)(ws + ((size_t)16 << 20));   //  8 MB: V^T [16][64][4096] (tau-permuted keys)
    short* xb    = (short*)(ws + ((size_t)24 << 20));   //  8 MB: x bf16 (dead after gemm)
    short* wtb   = (short*)(ws + ((size_t)32 << 20));   //  6 MB: w^T bf16 (dead after gemm)
    float* opart = (float*)(ws + ((size_t)24 << 20));   // 16 MB: split-1 partial O (reuses xb/wtb)
    float* ls0   = (float*)(ws + ((size_t)40 << 20));   // 256 KB
    float* ls1   = (float*)(ws + ((size_t)40 << 20) + (256 << 10));
    int*   flags = (int*)  (ws + ((size_t)40 << 20) + (512 << 10));  // 2 KB

    cvt_fused<<<2048 + 768, 256, 0, stream>>>(x, w, xb, wtb, flags);
    qkv_gemm <<<dim3(SEQ / 128, 3072 / 128), 256, 0, stream>>>(xb, wtb, kq, vt);
    attn     <<<1024, 256, 0, stream>>>(kq, vt, out, opart, ls0, ls1, flags);
}

// Round 9
// 254.441 us; speedup vs baseline: 1.6888x; 1.6888x over previous
//
#include <hip/hip_runtime.h>
#include <stdint.h>
#include <math.h>

#define SEQ 4096
#define DM  1024
#define NH  16
#define DH  64
#define LOG2E 1.44269504088896341f

typedef short bf16x8 __attribute__((ext_vector_type(8)));
typedef short bf16x4 __attribute__((ext_vector_type(4)));
typedef float f32x4  __attribute__((ext_vector_type(4)));
typedef uint32_t u32x4 __attribute__((ext_vector_type(4)));

typedef const __attribute__((address_space(1))) short* gptr_t;
typedef __attribute__((address_space(3))) short* lptr_t;

__device__ __forceinline__ short f2bf(float f) {
    union { float f; uint32_t u; } x; x.f = f;
    uint32_t r = (x.u + 0x7fffu + ((x.u >> 16) & 1u)) >> 16;
    return (short)r;
}
// pack two f32 -> dword of two truncated bf16 (lo in low half) — plain bit
// ops, fully schedulable (inline-asm variants measured -35%; m240)
__device__ __forceinline__ uint32_t pkbf(float lo, float hi) {
    union { float f; uint32_t u; } a, b; a.f = lo; b.f = hi;
    return (a.u >> 16) | (b.u & 0xffff0000u);
}

__device__ __forceinline__ void load_lds16(const short* g, const short* l) {
    __builtin_amdgcn_global_load_lds((gptr_t)(uintptr_t)g,
                                     (lptr_t)(uint32_t)(uintptr_t)l, 16, 0, 0);
}

// raw workgroup barrier with compiler memory fence (no vmcnt auto-drain)
__device__ __forceinline__ void wgbar() {
    asm volatile("" ::: "memory");
    __builtin_amdgcn_s_barrier();
    asm volatile("" ::: "memory");
}
#define WAITVM(n) asm volatile("s_waitcnt vmcnt(" #n ")" ::: "memory")
#define WAITLGKM(n) do { asm volatile("s_waitcnt lgkmcnt(" #n ")" ::: "memory"); \
                         __builtin_amdgcn_sched_barrier(0); } while (0)
#define DSR(d, a, o) asm volatile("ds_read_b128 %0, %1 offset:" o : "=v"(d) : "v"(a))

// ---- fused prep: blocks [0,2048) convert x fp32->bf16; blocks [2048,2816)
//      transpose w [1024][3072] -> wtb [3072][1024] bf16, Q cols pre-scaled ----
__global__ __launch_bounds__(256) void cvt_fused(const float* __restrict__ x,
                                                 const float* __restrict__ w,
                                                 short* __restrict__ xb,
                                                 short* __restrict__ wtb) {
    __shared__ float T[64][69];
    const int b = blockIdx.x;
    if (b < 2048) {
        const int i = (b * 256 + threadIdx.x) * 8;
        float4 a0 = ((const float4*)(x + i))[0];
        float4 a1 = ((const float4*)(x + i))[1];
        bf16x8 p;
        p[0]=f2bf(a0.x); p[1]=f2bf(a0.y); p[2]=f2bf(a0.z); p[3]=f2bf(a0.w);
        p[4]=f2bf(a1.x); p[5]=f2bf(a1.y); p[6]=f2bf(a1.z); p[7]=f2bf(a1.w);
        *(bf16x8*)(xb + i) = p;
        return;
    }
    const int bb = b - 2048;
    const int n0 = (bb % 48) * 64, k0 = (bb / 48) * 64;
    const int t = threadIdx.x;
    {
        const int kr = t >> 4, nc = (t & 15) * 4;
        #pragma unroll
        for (int i = 0; i < 4; ++i) {
            float4 v = *(const float4*)(w + (size_t)(k0 + kr + i * 16) * 3072 + n0 + nc);
            T[kr + i * 16][nc + 0] = v.x; T[kr + i * 16][nc + 1] = v.y;
            T[kr + i * 16][nc + 2] = v.z; T[kr + i * 16][nc + 3] = v.w;
        }
    }
    __syncthreads();
    const int nr = t >> 4, kc = (t & 15) * 4;
    #pragma unroll
    for (int i = 0; i < 4; ++i) {
        const int n = n0 + nr + i * 16;
        const float sc = (n >= 1024 && n < 2048) ? (LOG2E / 32.0f) : 1.0f;
        short4 o;
        o.x = f2bf(T[kc + 0][nr + i * 16] * sc);
        o.y = f2bf(T[kc + 1][nr + i * 16] * sc);
        o.z = f2bf(T[kc + 2][nr + i * 16] * sc);
        o.w = f2bf(T[kc + 3][nr + i * 16] * sc);
        *(short4*)(wtb + (size_t)n * 1024 + k0 + kc) = o;
    }
}

// ---- QKV GEMM v7 (proven): 128x128 tile, BK=64, distance-2 prefetch,
//      counted vmcnt(8), raw barriers, XOR-8 swizzled LDS, asm ds_read.
//      (Asm pinning is SAFE here: ~pure-MFMA loop, unlike attn's.) ----
__global__ __launch_bounds__(256, 2) void qkv_gemm(const short* __restrict__ xb,
                                                   const short* __restrict__ wtb,
                                                   short* __restrict__ kq,
                                                   short* __restrict__ vt) {
    __shared__ short As[2][8192];
    __shared__ short Bs[2][8192];
    const int col0 = blockIdx.y * 128, row0 = blockIdx.x * 128;
    const int tid = threadIdx.x, w = tid >> 6, lane = tid & 63;
    const int lmod = lane & 15, ldiv = lane >> 4;
    const int wr = (w >> 1) * 64, wc = (w & 1) * 64;

    const int srow = w * 32 + (lane >> 3);
    const int slc  = (lane & 7) ^ ((lane >> 3) & 7);
    const short* gA = xb  + (size_t)(row0 + srow) * 1024 + slc * 8;
    const short* gB = wtb + (size_t)(col0 + srow) * 1024 + slc * 8;
    short* lA = &As[0][0] + w * 2048;
    short* lB = &Bs[0][0] + w * 2048;

    const uint32_t asb = (uint32_t)(uintptr_t)&As[0][0];
    const uint32_t bsb = (uint32_t)(uintptr_t)&Bs[0][0];
    const int xorm = lmod & 7;
    const int rdA = (wr + lmod) * 128 + ((ldiv ^ xorm) << 4);
    const int rdB = (wc + lmod) * 128 + ((ldiv ^ xorm) << 4);

    f32x4 acc[4][4] = {};

    auto stage = [&](int kt, int p) {
        const short* ga = gA + kt * 64;
        const short* gb = gB + kt * 64;
        short* la = lA + p * 8192;
        short* lb = lB + p * 8192;
        #pragma unroll
        for (int q = 0; q < 4; ++q) {
            load_lds16(ga + q * 8192, la + q * 512);
            load_lds16(gb + q * 8192, lb + q * 512);
        }
    };

    stage(0, 0);
    stage(1, 1);
    WAITVM(8);
    wgbar();

    for (int t = 0; t < 16; ++t) {
        const int poff = (t & 1) << 14;
        const int aA0 = (int)asb + poff + rdA, aA1 = aA0 ^ 64;
        const int bA0 = (int)bsb + poff + rdB, bA1 = bA0 ^ 64;
        bf16x8 a0[4], a1[4], b0[4], b1[4];
        DSR(a0[0], aA0, "0");    DSR(a0[1], aA0, "2048");
        DSR(a0[2], aA0, "4096"); DSR(a0[3], aA0, "6144");
        DSR(b0[0], bA0, "0");    DSR(b0[1], bA0, "2048");
        DSR(b0[2], bA0, "4096"); DSR(b0[3], bA0, "6144");
        DSR(a1[0], aA1, "0");    DSR(a1[1], aA1, "2048");
        DSR(a1[2], aA1, "4096"); DSR(a1[3], aA1, "6144");
        DSR(b1[0], bA1, "0");    DSR(b1[1], bA1, "2048");
        DSR(b1[2], bA1, "4096"); DSR(b1[3], bA1, "6144");
        WAITLGKM(8);
        #pragma unroll
        for (int i = 0; i < 4; ++i)
            #pragma unroll
            for (int j = 0; j < 4; ++j)
                acc[i][j] = __builtin_amdgcn_mfma_f32_16x16x32_bf16(a0[i], b0[j], acc[i][j], 0, 0, 0);
        WAITLGKM(0);
        #pragma unroll
        for (int i = 0; i < 4; ++i)
            #pragma unroll
            for (int j = 0; j < 4; ++j)
                acc[i][j] = __builtin_amdgcn_mfma_f32_16x16x32_bf16(a1[i], b1[j], acc[i][j], 0, 0, 0);

        wgbar();
        if (t + 2 < 16) {
            stage(t + 2, t & 1);
            WAITVM(8);
            wgbar();
        } else if (t + 1 < 16) {
            WAITVM(0);
            wgbar();
        }
    }

    if (col0 < 2048) {
        #pragma unroll
        for (int i = 0; i < 4; ++i)
            #pragma unroll
            for (int j = 0; j < 4; ++j)
                #pragma unroll
                for (int r = 0; r < 4; ++r)
                    kq[(size_t)(row0 + wr + i * 16 + ldiv * 4 + r) * 2048
                       + col0 + wc + j * 16 + lmod] = f2bf(acc[i][j][r]);
    } else {
        #pragma unroll
        for (int i = 0; i < 4; ++i) {
            const int ig = row0 + wr + i * 16 + ldiv * 4;
            const int kk = ig & 63;
            // tau: 32a+16b+4c -> 32a+8c+4b
            const int kkp = (kk & 32) | ((kk & 12) << 1) | ((kk & 16) >> 2);
            const int igp = (ig & ~63) | kkp;
            #pragma unroll
            for (int j = 0; j < 4; ++j) {
                const int cg = col0 + wc + j * 16 + lmod - 2048;
                const int h = cg >> 6, d = cg & 63;
                bf16x4 p;
                p[0]=f2bf(acc[i][j][0]); p[1]=f2bf(acc[i][j][1]);
                p[2]=f2bf(acc[i][j][2]); p[3]=f2bf(acc[i][j][3]);
                *(bf16x4*)(vt + (size_t)(h * 64 + d) * SEQ + igp) = p;
            }
        }
    }
}

// ---- flash attention, split-K 2-way.
//  v10 = v6 compute body VERBATIM (zero asm in loop) + KVBLK=128 pairing:
//  stage TWO 64-key tiles into 4 static LDS buffers per phase, ONE
//  drain barrier per pair (halves barrier count / exposed latency events).
//  32KB LDS -> still 4 blocks/CU. Separate combine kernel (v9's fused
//  combine with __threadfence invalidated L2 device-wide: 327us). ----
__global__ __launch_bounds__(256, 4) void attn(const short* __restrict__ kq,
                                               const short* __restrict__ vt,
                                               float* __restrict__ o0,
                                               float* __restrict__ o1,
                                               float* __restrict__ ls0,
                                               float* __restrict__ ls1) {
    __shared__ short Ks0[4096], Vs0[4096];
    __shared__ short Ks1[4096], Vs1[4096];

    // band-interleaved decode: per-CU resident set sums to 66 units
    const int b = blockIdx.x;
    const int band = b >> 8, pos = b & 255, g = pos >> 5;
    const int qt = (band & 1) ? (24 - band * 8 + g) : (31 - band * 8 - g);
    const int h = (pos >> 1) & 15, s = pos & 1;

    const int tid = threadIdx.x, w = tid >> 6, lane = tid & 63;
    const int lmod = lane & 15, ldiv = lane >> 4;
    const float slope2 = exp2f(-0.5f * (float)(h + 1)) * LOG2E;

    // staging: wave w stages rows w*16..w*16+15 of both K and V tiles.
    const int sr0 = w * 16 + (lane >> 3), sr1 = sr0 + 8;
    const int sc0 = (lane & 7) ^ (sr0 & 7), sc1 = (lane & 7) ^ (sr1 & 7);

    const int xorm = lmod & 7;                 // read-side swizzle
    const int cxs0 = (ldiv ^ xorm) * 8;        // phys short offset, chunk ldiv
    const int cxs1 = ((4 + ldiv) ^ xorm) * 8;  // phys short offset, chunk 4+ldiv

    const int rowbase = qt * 128 + w * 32;

    // Q fragments (2 m-blocks x 2 d-chunks) — the MFMA B operand
    bf16x8 qf[2][2];
    #pragma unroll
    for (int m = 0; m < 2; ++m) {
        const short* qp = kq + (size_t)(rowbase + m * 16 + lmod) * 2048 + 1024 + h * 64;
        qf[m][0] = *(const bf16x8*)(qp + ldiv * 8);
        qf[m][1] = *(const bf16x8*)(qp + 32 + ldiv * 8);
    }
    // swapped layout: lane holds S[k = kt*64 + nt*16 + 4*ldiv + r][q = lmod]
    int db2[2];
    float pre[2][4];
    #pragma unroll
    for (int m = 0; m < 2; ++m) {
        db2[m] = 4 * ldiv - (rowbase + m * 16 + lmod);
        #pragma unroll
        for (int r = 0; r < 4; ++r) pre[m][r] = slope2 * (float)(db2[m] + r);
    }

    f32x4 O[2][4] = {};
    float lsum[2] = {};
    const int kt0 = s ? (qt + 1) : 0;
    const int kt1 = s ? (2 * qt + 2) : (qt + 1);
    const int n = kt1 - kt0;

    auto stage = [&](int kt_, short* Kd, short* Vd) {
        const short* kb = kq + (size_t)(kt_ * 64) * 2048 + h * 64;
        load_lds16(kb + (size_t)sr0 * 2048 + sc0 * 8, Kd + (w * 16) * 64);
        load_lds16(kb + (size_t)sr1 * 2048 + sc1 * 8, Kd + (w * 16 + 8) * 64);
        const short* vb = vt + (size_t)(h * 64) * SEQ + kt_ * 64;
        load_lds16(vb + (size_t)sr0 * SEQ + sc0 * 8, Vd + (w * 16) * 64);
        load_lds16(vb + (size_t)sr1 * SEQ + sc1 * 8, Vd + (w * 16 + 8) * 64);
    };

    auto compute = [&](int kt, const short* Ksb, const short* Vsb) {
        const bool diag = (kt >= 2 * qt);
        const int dt = kt * 64;
        const float cb = slope2 * (float)dt;

        #pragma unroll
        for (int ks = 0; ks < 2; ++ks) {       // 32-key chunk for PV
            u32x4 pk0, pk1;
            #pragma unroll
            for (int j1 = 0; j1 < 2; ++j1) {   // K 16-row block nt = 2ks+j1
                const int nt = ks * 2 + j1;
                const float cn = cb + slope2 * (float)(nt * 16);
                f32x4 s0, s1;
                #pragma unroll
                for (int r = 0; r < 4; ++r) { s0[r] = pre[0][r] + cn; s1[r] = pre[1][r] + cn; }
                const short* krow = Ksb + (nt * 16 + lmod) * 64;
                const bf16x8 kf0 = *(const bf16x8*)(krow + cxs0);
                const bf16x8 kf1 = *(const bf16x8*)(krow + cxs1);
                s0 = __builtin_amdgcn_mfma_f32_16x16x32_bf16(kf0, qf[0][0], s0, 0, 0, 0);
                s0 = __builtin_amdgcn_mfma_f32_16x16x32_bf16(kf1, qf[0][1], s0, 0, 0, 0);
                s1 = __builtin_amdgcn_mfma_f32_16x16x32_bf16(kf0, qf[1][0], s1, 0, 0, 0);
                s1 = __builtin_amdgcn_mfma_f32_16x16x32_bf16(kf1, qf[1][1], s1, 0, 0, 0);

                float p0[4], p1[4];
                if (diag) {
                    #pragma unroll
                    for (int r = 0; r < 4; ++r) {
                        float v0 = s0[r], v1 = s1[r];
                        if (dt + nt * 16 + r + db2[0] > 0) v0 = -1e30f;
                        if (dt + nt * 16 + r + db2[1] > 0) v1 = -1e30f;
                        p0[r] = __builtin_amdgcn_exp2f(v0);
                        p1[r] = __builtin_amdgcn_exp2f(v1);
                    }
                } else {
                    #pragma unroll
                    for (int r = 0; r < 4; ++r) {
                        p0[r] = __builtin_amdgcn_exp2f(s0[r]);
                        p1[r] = __builtin_amdgcn_exp2f(s1[r]);
                    }
                }
                lsum[0] += (p0[0] + p0[1]) + (p0[2] + p0[3]);
                lsum[1] += (p1[0] + p1[1]) + (p1[2] + p1[3]);
                pk0[j1 * 2]     = pkbf(p0[0], p0[1]);
                pk0[j1 * 2 + 1] = pkbf(p0[2], p0[3]);
                pk1[j1 * 2]     = pkbf(p1[0], p1[1]);
                pk1[j1 * 2 + 1] = pkbf(p1[2], p1[3]);
            }
            const bf16x8 pa0 = __builtin_bit_cast(bf16x8, pk0);
            const bf16x8 pa1 = __builtin_bit_cast(bf16x8, pk1);
            const int cxo = ks ? cxs1 : cxs0;
            #pragma unroll
            for (int nt2 = 0; nt2 < 4; ++nt2) {
                const bf16x8 vf = *(const bf16x8*)(Vsb + (nt2 * 16 + lmod) * 64 + cxo);
                O[0][nt2] = __builtin_amdgcn_mfma_f32_16x16x32_bf16(pa0, vf, O[0][nt2], 0, 0, 0);
                O[1][nt2] = __builtin_amdgcn_mfma_f32_16x16x32_bf16(pa1, vf, O[1][nt2], 0, 0, 0);
            }
        }
    };

    int kt = kt0;
    for (int p = 0; p < (n >> 1); ++p) {
        __syncthreads();                // prev pair's reads done
        stage(kt, Ks0, Vs0);
        stage(kt + 1, Ks1, Vs1);
        __syncthreads();                // vmcnt drained -> both tiles ready
        compute(kt, Ks0, Vs0);
        compute(kt + 1, Ks1, Vs1);
        kt += 2;
    }
    if (n & 1) {
        __syncthreads();
        stage(kt, Ks0, Vs0);
        __syncthreads();
        compute(kt, Ks0, Vs0);
    }

    // row sums: lane holds partial for q = lmod; reduce across ldiv groups
    #pragma unroll
    for (int m = 0; m < 2; ++m) {
        float v = lsum[m];
        v += __shfl_xor(v, 16);
        v += __shfl_xor(v, 32);
        lsum[m] = v;
    }

    float* ob = s ? o1 : o0;
    float* lb = s ? ls1 : ls0;
    #pragma unroll
    for (int m = 0; m < 2; ++m) {
        const int i0 = rowbase + m * 16 + ldiv * 4;
        #pragma unroll
        for (int nt2 = 0; nt2 < 4; ++nt2)
            #pragma unroll
            for (int r = 0; r < 4; ++r)
                ob[(size_t)(i0 + r) * DM + h * 64 + nt2 * 16 + lmod] = O[m][nt2][r];
    }
    if (ldiv == 0) {
        #pragma unroll
        for (int m = 0; m < 2; ++m)
            lb[h * SEQ + rowbase + m * 16 + lmod] = lsum[m];
    }
}

// ---- combine: out = (O0 + O1) / (l0 + l1) ----
__global__ __launch_bounds__(256) void combine(float* __restrict__ out,
                                               const float* __restrict__ opart,
                                               const float* __restrict__ ls0,
                                               const float* __restrict__ ls1) {
    const int i8 = (blockIdx.x * 256 + threadIdx.x) * 8;
    const int row = i8 >> 10, col = i8 & 1023, h = col >> 6;
    const float l = ls0[h * SEQ + row] + ls1[h * SEQ + row];
    const float rc = 1.0f / l;
    float4 a0 = *(const float4*)(out + i8);
    float4 a1 = *(const float4*)(out + i8 + 4);
    float4 b0 = *(const float4*)(opart + i8);
    float4 b1 = *(const float4*)(opart + i8 + 4);
    float4 c0, c1;
    c0.x = (a0.x + b0.x) * rc; c0.y = (a0.y + b0.y) * rc;
    c0.z = (a0.z + b0.z) * rc; c0.w = (a0.w + b0.w) * rc;
    c1.x = (a1.x + b1.x) * rc; c1.y = (a1.y + b1.y) * rc;
    c1.z = (a1.z + b1.z) * rc; c1.w = (a1.w + b1.w) * rc;
    *(float4*)(out + i8) = c0;
    *(float4*)(out + i8 + 4) = c1;
}

extern "C" void kernel_launch(void* const* d_in, const int* in_sizes, int n_in,
                              void* d_out, int out_size, void* d_ws, size_t ws_size,
                              hipStream_t stream) {
    const float* x = (const float*)d_in[0];   // [1,4096,1024] fp32
    const float* w = (const float*)d_in[1];   // [1024,3072] fp32
    float* out = (float*)d_out;

    char* ws = (char*)d_ws;
    short* kq    = (short*)(ws);                        // 16 MB: K|Q [4096][2048]
    short* vt    = (short*)(ws + ((size_t)16 << 20));   //  8 MB: V^T [16][64][4096] (tau-permuted keys)
    short* xb    = (short*)(ws + ((size_t)24 << 20));   //  8 MB: x bf16 (dead after gemm)
    short* wtb   = (short*)(ws + ((size_t)32 << 20));   //  6 MB: w^T bf16 (dead after gemm)
    float* opart = (float*)(ws + ((size_t)24 << 20));   // 16 MB: split-1 partial O (reuses xb/wtb)
    float* ls0   = (float*)(ws + ((size_t)40 << 20));   // 256 KB
    float* ls1   = (float*)(ws + ((size_t)40 << 20) + (256 << 10));

    cvt_fused<<<2048 + 768, 256, 0, stream>>>(x, w, xb, wtb);
    qkv_gemm <<<dim3(SEQ / 128, 3072 / 128), 256, 0, stream>>>(xb, wtb, kq, vt);
    attn     <<<1024, 256, 0, stream>>>(kq, vt, out, opart, ls0, ls1);
    combine  <<<SEQ * DM / (256 * 8), 256, 0, stream>>>(out, opart, ls0, ls1);
}

// Round 10
// 163.262 us; speedup vs baseline: 2.6320x; 1.5585x over previous
//
#include <hip/hip_runtime.h>
#include <stdint.h>
#include <math.h>

#define SEQ 4096
#define DM  1024
#define NH  16
#define DH  64
#define LOG2E 1.44269504088896341f

typedef short bf16x8 __attribute__((ext_vector_type(8)));
typedef short bf16x4 __attribute__((ext_vector_type(4)));
typedef float f32x4  __attribute__((ext_vector_type(4)));
typedef uint32_t u32x4 __attribute__((ext_vector_type(4)));

typedef const __attribute__((address_space(1))) short* gptr_t;
typedef __attribute__((address_space(3))) short* lptr_t;

__device__ __forceinline__ short f2bf(float f) {
    union { float f; uint32_t u; } x; x.f = f;
    uint32_t r = (x.u + 0x7fffu + ((x.u >> 16) & 1u)) >> 16;
    return (short)r;
}
// pack two f32 -> dword of two truncated bf16 (lo in low half) — plain bit
// ops, fully schedulable (inline-asm variants measured -35%; m240)
__device__ __forceinline__ uint32_t pkbf(float lo, float hi) {
    union { float f; uint32_t u; } a, b; a.f = lo; b.f = hi;
    return (a.u >> 16) | (b.u & 0xffff0000u);
}

__device__ __forceinline__ void load_lds16(const short* g, const short* l) {
    __builtin_amdgcn_global_load_lds((gptr_t)(uintptr_t)g,
                                     (lptr_t)(uint32_t)(uintptr_t)l, 16, 0, 0);
}

// raw workgroup barrier with compiler memory fence (no vmcnt auto-drain)
__device__ __forceinline__ void wgbar() {
    asm volatile("" ::: "memory");
    __builtin_amdgcn_s_barrier();
    asm volatile("" ::: "memory");
}
#define WAITVM(n) asm volatile("s_waitcnt vmcnt(" #n ")" ::: "memory")
#define WAITLGKM(n) do { asm volatile("s_waitcnt lgkmcnt(" #n ")" ::: "memory"); \
                         __builtin_amdgcn_sched_barrier(0); } while (0)
#define DSR(d, a, o) asm volatile("ds_read_b128 %0, %1 offset:" o : "=v"(d) : "v"(a))

// ---- fused prep: blocks [0,2048) convert x fp32->bf16; blocks [2048,2816)
//      transpose w [1024][3072] -> wtb [3072][1024] bf16, Q cols pre-scaled ----
__global__ __launch_bounds__(256) void cvt_fused(const float* __restrict__ x,
                                                 const float* __restrict__ w,
                                                 short* __restrict__ xb,
                                                 short* __restrict__ wtb) {
    __shared__ float T[64][69];
    const int b = blockIdx.x;
    if (b < 2048) {
        const int i = (b * 256 + threadIdx.x) * 8;
        float4 a0 = ((const float4*)(x + i))[0];
        float4 a1 = ((const float4*)(x + i))[1];
        bf16x8 p;
        p[0]=f2bf(a0.x); p[1]=f2bf(a0.y); p[2]=f2bf(a0.z); p[3]=f2bf(a0.w);
        p[4]=f2bf(a1.x); p[5]=f2bf(a1.y); p[6]=f2bf(a1.z); p[7]=f2bf(a1.w);
        *(bf16x8*)(xb + i) = p;
        return;
    }
    const int bb = b - 2048;
    const int n0 = (bb % 48) * 64, k0 = (bb / 48) * 64;
    const int t = threadIdx.x;
    {
        const int kr = t >> 4, nc = (t & 15) * 4;
        #pragma unroll
        for (int i = 0; i < 4; ++i) {
            float4 v = *(const float4*)(w + (size_t)(k0 + kr + i * 16) * 3072 + n0 + nc);
            T[kr + i * 16][nc + 0] = v.x; T[kr + i * 16][nc + 1] = v.y;
            T[kr + i * 16][nc + 2] = v.z; T[kr + i * 16][nc + 3] = v.w;
        }
    }
    __syncthreads();
    const int nr = t >> 4, kc = (t & 15) * 4;
    #pragma unroll
    for (int i = 0; i < 4; ++i) {
        const int n = n0 + nr + i * 16;
        const float sc = (n >= 1024 && n < 2048) ? (LOG2E / 32.0f) : 1.0f;
        short4 o;
        o.x = f2bf(T[kc + 0][nr + i * 16] * sc);
        o.y = f2bf(T[kc + 1][nr + i * 16] * sc);
        o.z = f2bf(T[kc + 2][nr + i * 16] * sc);
        o.w = f2bf(T[kc + 3][nr + i * 16] * sc);
        *(short4*)(wtb + (size_t)n * 1024 + k0 + kc) = o;
    }
}

// ---- QKV GEMM v11: v7 loop (proven: distance-2 prefetch, counted vmcnt(8),
//      raw barriers, XOR-8 swizzled LDS, asm ds_read — safe in a ~pure-MFMA
//      loop) + split output layouts:
//        K  -> kq_k [4096][1024] seq-major (scalar stores; staging needs
//              d-contiguous 16B chunks, so K cannot transpose)
//        Q  -> qT   [1024][4096] d-major, bf16x4 vectorized stores
//        V  -> vt   tau-permuted, bf16x4 (unchanged) ----
__global__ __launch_bounds__(256, 2) void qkv_gemm(const short* __restrict__ xb,
                                                   const short* __restrict__ wtb,
                                                   short* __restrict__ kq_k,
                                                   short* __restrict__ qT,
                                                   short* __restrict__ vt) {
    __shared__ short As[2][8192];
    __shared__ short Bs[2][8192];
    const int col0 = blockIdx.y * 128, row0 = blockIdx.x * 128;
    const int tid = threadIdx.x, w = tid >> 6, lane = tid & 63;
    const int lmod = lane & 15, ldiv = lane >> 4;
    const int wr = (w >> 1) * 64, wc = (w & 1) * 64;

    const int srow = w * 32 + (lane >> 3);
    const int slc  = (lane & 7) ^ ((lane >> 3) & 7);
    const short* gA = xb  + (size_t)(row0 + srow) * 1024 + slc * 8;
    const short* gB = wtb + (size_t)(col0 + srow) * 1024 + slc * 8;
    short* lA = &As[0][0] + w * 2048;
    short* lB = &Bs[0][0] + w * 2048;

    const uint32_t asb = (uint32_t)(uintptr_t)&As[0][0];
    const uint32_t bsb = (uint32_t)(uintptr_t)&Bs[0][0];
    const int xorm = lmod & 7;
    const int rdA = (wr + lmod) * 128 + ((ldiv ^ xorm) << 4);
    const int rdB = (wc + lmod) * 128 + ((ldiv ^ xorm) << 4);

    f32x4 acc[4][4] = {};

    auto stage = [&](int kt, int p) {
        const short* ga = gA + kt * 64;
        const short* gb = gB + kt * 64;
        short* la = lA + p * 8192;
        short* lb = lB + p * 8192;
        #pragma unroll
        for (int q = 0; q < 4; ++q) {
            load_lds16(ga + q * 8192, la + q * 512);
            load_lds16(gb + q * 8192, lb + q * 512);
        }
    };

    stage(0, 0);
    stage(1, 1);
    WAITVM(8);
    wgbar();

    for (int t = 0; t < 16; ++t) {
        const int poff = (t & 1) << 14;
        const int aA0 = (int)asb + poff + rdA, aA1 = aA0 ^ 64;
        const int bA0 = (int)bsb + poff + rdB, bA1 = bA0 ^ 64;
        bf16x8 a0[4], a1[4], b0[4], b1[4];
        DSR(a0[0], aA0, "0");    DSR(a0[1], aA0, "2048");
        DSR(a0[2], aA0, "4096"); DSR(a0[3], aA0, "6144");
        DSR(b0[0], bA0, "0");    DSR(b0[1], bA0, "2048");
        DSR(b0[2], bA0, "4096"); DSR(b0[3], bA0, "6144");
        DSR(a1[0], aA1, "0");    DSR(a1[1], aA1, "2048");
        DSR(a1[2], aA1, "4096"); DSR(a1[3], aA1, "6144");
        DSR(b1[0], bA1, "0");    DSR(b1[1], bA1, "2048");
        DSR(b1[2], bA1, "4096"); DSR(b1[3], bA1, "6144");
        WAITLGKM(8);
        #pragma unroll
        for (int i = 0; i < 4; ++i)
            #pragma unroll
            for (int j = 0; j < 4; ++j)
                acc[i][j] = __builtin_amdgcn_mfma_f32_16x16x32_bf16(a0[i], b0[j], acc[i][j], 0, 0, 0);
        WAITLGKM(0);
        #pragma unroll
        for (int i = 0; i < 4; ++i)
            #pragma unroll
            for (int j = 0; j < 4; ++j)
                acc[i][j] = __builtin_amdgcn_mfma_f32_16x16x32_bf16(a1[i], b1[j], acc[i][j], 0, 0, 0);

        wgbar();
        if (t + 2 < 16) {
            stage(t + 2, t & 1);
            WAITVM(8);
            wgbar();
        } else if (t + 1 < 16) {
            WAITVM(0);
            wgbar();
        }
    }

    if (col0 < 1024) {
        // K: seq-major, scalar stores (layout fixed by attn staging needs)
        #pragma unroll
        for (int i = 0; i < 4; ++i)
            #pragma unroll
            for (int j = 0; j < 4; ++j)
                #pragma unroll
                for (int r = 0; r < 4; ++r)
                    kq_k[(size_t)(row0 + wr + i * 16 + ldiv * 4 + r) * 1024
                         + col0 + wc + j * 16 + lmod] = f2bf(acc[i][j][r]);
    } else if (col0 < 2048) {
        // Q: d-major qT[1024][4096], vectorized bf16x4 along seq
        #pragma unroll
        for (int i = 0; i < 4; ++i) {
            const int ig = row0 + wr + i * 16 + ldiv * 4;
            #pragma unroll
            for (int j = 0; j < 4; ++j) {
                const int dg = col0 + wc + j * 16 + lmod - 1024;
                bf16x4 p;
                p[0]=f2bf(acc[i][j][0]); p[1]=f2bf(acc[i][j][1]);
                p[2]=f2bf(acc[i][j][2]); p[3]=f2bf(acc[i][j][3]);
                *(bf16x4*)(qT + (size_t)dg * SEQ + ig) = p;
            }
        }
    } else {
        #pragma unroll
        for (int i = 0; i < 4; ++i) {
            const int ig = row0 + wr + i * 16 + ldiv * 4;
            const int kk = ig & 63;
            // tau: 32a+16b+4c -> 32a+8c+4b
            const int kkp = (kk & 32) | ((kk & 12) << 1) | ((kk & 16) >> 2);
            const int igp = (ig & ~63) | kkp;
            #pragma unroll
            for (int j = 0; j < 4; ++j) {
                const int cg = col0 + wc + j * 16 + lmod - 2048;
                const int h = cg >> 6, d = cg & 63;
                bf16x4 p;
                p[0]=f2bf(acc[i][j][0]); p[1]=f2bf(acc[i][j][1]);
                p[2]=f2bf(acc[i][j][2]); p[3]=f2bf(acc[i][j][3]);
                *(bf16x4*)(vt + (size_t)(h * 64 + d) * SEQ + igp) = p;
            }
        }
    }
}

// ---- flash attention, split-K 2-way.
//  v11 = round-6 best attn VERBATIM (single-buffer LDS, 2-barrier staging,
//  zero asm in the loop, straight-line body — every restructure regressed:
//  asm pinning v4/v5/v8, fence-fusion v9, lambda/KVBLK v10 loop-spill)
//  except: K staged from kq_k (stride 1024) and Q read from d-major qT
//  (32 scalar 32B-coalesced L2-hot loads, once per block). ----
__global__ __launch_bounds__(256, 4) void attn(const short* __restrict__ kq_k,
                                               const short* __restrict__ qT,
                                               const short* __restrict__ vt,
                                               float* __restrict__ o0,
                                               float* __restrict__ o1,
                                               float* __restrict__ ls0,
                                               float* __restrict__ ls1) {
    __shared__ short Ks[64 * 64];
    __shared__ short Vs[64 * 64];

    // band-interleaved decode: per-CU resident set sums to 66 units
    const int b = blockIdx.x;
    const int band = b >> 8, pos = b & 255, g = pos >> 5;
    const int qt = (band & 1) ? (24 - band * 8 + g) : (31 - band * 8 - g);
    const int h = (pos >> 1) & 15, s = pos & 1;

    const int tid = threadIdx.x, w = tid >> 6, lane = tid & 63;
    const int lmod = lane & 15, ldiv = lane >> 4;
    const float slope2 = exp2f(-0.5f * (float)(h + 1)) * LOG2E;

    // staging: wave w stages rows w*16..w*16+15 of both K and V tiles.
    const int sr0 = w * 16 + (lane >> 3), sr1 = sr0 + 8;
    const int sc0 = (lane & 7) ^ (sr0 & 7), sc1 = (lane & 7) ^ (sr1 & 7);

    const int xorm = lmod & 7;                 // read-side swizzle
    const int cxs0 = (ldiv ^ xorm) * 8;        // phys short offset, chunk ldiv
    const int cxs1 = ((4 + ldiv) ^ xorm) * 8;  // phys short offset, chunk 4+ldiv

    const int rowbase = qt * 128 + w * 32;

    // Q fragments (2 m-blocks x 2 d-chunks) from d-major qT:
    // qf[m][c][j] = Q[rowbase+m*16+lmod][d = c*32 + ldiv*8 + j]
    bf16x8 qf[2][2];
    {
        const short* qb = qT + (size_t)(h * 64) * SEQ + rowbase + lmod;
        #pragma unroll
        for (int m = 0; m < 2; ++m)
            #pragma unroll
            for (int c = 0; c < 2; ++c)
                #pragma unroll
                for (int j = 0; j < 8; ++j)
                    qf[m][c][j] = qb[(size_t)(c * 32 + ldiv * 8 + j) * SEQ + m * 16];
    }
    // swapped layout: lane holds S[k = kt*64 + nt*16 + 4*ldiv + r][q = lmod]
    int db2[2];
    float pre[2][4];
    #pragma unroll
    for (int m = 0; m < 2; ++m) {
        db2[m] = 4 * ldiv - (rowbase + m * 16 + lmod);
        #pragma unroll
        for (int r = 0; r < 4; ++r) pre[m][r] = slope2 * (float)(db2[m] + r);
    }

    f32x4 O[2][4] = {};
    float lsum[2] = {};
    const int kt0 = s ? (qt + 1) : 0;
    const int kt1 = s ? (2 * qt + 2) : (qt + 1);

    for (int kt = kt0; kt < kt1; ++kt) {
        __syncthreads();   // prev compute done reading Ks/Vs
        {
            const short* kb = kq_k + (size_t)(kt * 64) * 1024 + h * 64;
            load_lds16(kb + (size_t)sr0 * 1024 + sc0 * 8, Ks + (w * 16) * 64);
            load_lds16(kb + (size_t)sr1 * 1024 + sc1 * 8, Ks + (w * 16 + 8) * 64);
            const short* vb = vt + (size_t)(h * 64) * SEQ + kt * 64;
            load_lds16(vb + (size_t)sr0 * SEQ + sc0 * 8, Vs + (w * 16) * 64);
            load_lds16(vb + (size_t)sr1 * SEQ + sc1 * 8, Vs + (w * 16 + 8) * 64);
        }
        __syncthreads();   // vmcnt drained -> LDS ready

        const bool diag = (kt >= 2 * qt);
        const int dt = kt * 64;
        const float cb = slope2 * (float)dt;

        #pragma unroll
        for (int ks = 0; ks < 2; ++ks) {       // 32-key chunk for PV
            u32x4 pk0, pk1;
            #pragma unroll
            for (int j1 = 0; j1 < 2; ++j1) {   // K 16-row block nt = 2ks+j1
                const int nt = ks * 2 + j1;
                const float cn = cb + slope2 * (float)(nt * 16);
                f32x4 s0, s1;
                #pragma unroll
                for (int r = 0; r < 4; ++r) { s0[r] = pre[0][r] + cn; s1[r] = pre[1][r] + cn; }
                const short* krow = Ks + (nt * 16 + lmod) * 64;
                const bf16x8 kf0 = *(const bf16x8*)(krow + cxs0);
                const bf16x8 kf1 = *(const bf16x8*)(krow + cxs1);
                s0 = __builtin_amdgcn_mfma_f32_16x16x32_bf16(kf0, qf[0][0], s0, 0, 0, 0);
                s0 = __builtin_amdgcn_mfma_f32_16x16x32_bf16(kf1, qf[0][1], s0, 0, 0, 0);
                s1 = __builtin_amdgcn_mfma_f32_16x16x32_bf16(kf0, qf[1][0], s1, 0, 0, 0);
                s1 = __builtin_amdgcn_mfma_f32_16x16x32_bf16(kf1, qf[1][1], s1, 0, 0, 0);

                float p0[4], p1[4];
                if (diag) {
                    #pragma unroll
                    for (int r = 0; r < 4; ++r) {
                        float v0 = s0[r], v1 = s1[r];
                        if (dt + nt * 16 + r + db2[0] > 0) v0 = -1e30f;
                        if (dt + nt * 16 + r + db2[1] > 0) v1 = -1e30f;
                        p0[r] = __builtin_amdgcn_exp2f(v0);
                        p1[r] = __builtin_amdgcn_exp2f(v1);
                    }
                } else {
                    #pragma unroll
                    for (int r = 0; r < 4; ++r) {
                        p0[r] = __builtin_amdgcn_exp2f(s0[r]);
                        p1[r] = __builtin_amdgcn_exp2f(s1[r]);
                    }
                }
                lsum[0] += (p0[0] + p0[1]) + (p0[2] + p0[3]);
                lsum[1] += (p1[0] + p1[1]) + (p1[2] + p1[3]);
                pk0[j1 * 2]     = pkbf(p0[0], p0[1]);
                pk0[j1 * 2 + 1] = pkbf(p0[2], p0[3]);
                pk1[j1 * 2]     = pkbf(p1[0], p1[1]);
                pk1[j1 * 2 + 1] = pkbf(p1[2], p1[3]);
            }
            const bf16x8 pa0 = __builtin_bit_cast(bf16x8, pk0);
            const bf16x8 pa1 = __builtin_bit_cast(bf16x8, pk1);
            const int cxo = ks ? cxs1 : cxs0;
            #pragma unroll
            for (int nt2 = 0; nt2 < 4; ++nt2) {
                const bf16x8 vf = *(const bf16x8*)(Vs + (nt2 * 16 + lmod) * 64 + cxo);
                O[0][nt2] = __builtin_amdgcn_mfma_f32_16x16x32_bf16(pa0, vf, O[0][nt2], 0, 0, 0);
                O[1][nt2] = __builtin_amdgcn_mfma_f32_16x16x32_bf16(pa1, vf, O[1][nt2], 0, 0, 0);
            }
        }
    }

    // row sums: lane holds partial for q = lmod; reduce across ldiv groups
    #pragma unroll
    for (int m = 0; m < 2; ++m) {
        float v = lsum[m];
        v += __shfl_xor(v, 16);
        v += __shfl_xor(v, 32);
        lsum[m] = v;
    }

    float* ob = s ? o1 : o0;
    float* lb = s ? ls1 : ls0;
    #pragma unroll
    for (int m = 0; m < 2; ++m) {
        const int i0 = rowbase + m * 16 + ldiv * 4;
        #pragma unroll
        for (int nt2 = 0; nt2 < 4; ++nt2)
            #pragma unroll
            for (int r = 0; r < 4; ++r)
                ob[(size_t)(i0 + r) * DM + h * 64 + nt2 * 16 + lmod] = O[m][nt2][r];
    }
    if (ldiv == 0) {
        #pragma unroll
        for (int m = 0; m < 2; ++m)
            lb[h * SEQ + rowbase + m * 16 + lmod] = lsum[m];
    }
}

// ---- combine: out = (O0 + O1) / (l0 + l1) ----
__global__ __launch_bounds__(256) void combine(float* __restrict__ out,
                                               const float* __restrict__ opart,
                                               const float* __restrict__ ls0,
                                               const float* __restrict__ ls1) {
    const int i8 = (blockIdx.x * 256 + threadIdx.x) * 8;
    const int row = i8 >> 10, col = i8 & 1023, h = col >> 6;
    const float l = ls0[h * SEQ + row] + ls1[h * SEQ + row];
    const float rc = 1.0f / l;
    float4 a0 = *(const float4*)(out + i8);
    float4 a1 = *(const float4*)(out + i8 + 4);
    float4 b0 = *(const float4*)(opart + i8);
    float4 b1 = *(const float4*)(opart + i8 + 4);
    float4 c0, c1;
    c0.x = (a0.x + b0.x) * rc; c0.y = (a0.y + b0.y) * rc;
    c0.z = (a0.z + b0.z) * rc; c0.w = (a0.w + b0.w) * rc;
    c1.x = (a1.x + b1.x) * rc; c1.y = (a1.y + b1.y) * rc;
    c1.z = (a1.z + b1.z) * rc; c1.w = (a1.w + b1.w) * rc;
    *(float4*)(out + i8) = c0;
    *(float4*)(out + i8 + 4) = c1;
}

extern "C" void kernel_launch(void* const* d_in, const int* in_sizes, int n_in,
                              void* d_out, int out_size, void* d_ws, size_t ws_size,
                              hipStream_t stream) {
    const float* x = (const float*)d_in[0];   // [1,4096,1024] fp32
    const float* w = (const float*)d_in[1];   // [1024,3072] fp32
    float* out = (float*)d_out;

    char* ws = (char*)d_ws;
    short* kq_k  = (short*)(ws);                        //  8 MB: K [4096][1024] seq-major
    short* qT    = (short*)(ws + ((size_t)8  << 20));   //  8 MB: Q^T [1024][4096] d-major
    short* vt    = (short*)(ws + ((size_t)16 << 20));   //  8 MB: V^T [16][64][4096] (tau-permuted keys)
    short* xb    = (short*)(ws + ((size_t)24 << 20));   //  8 MB: x bf16 (dead after gemm)
    short* wtb   = (short*)(ws + ((size_t)32 << 20));   //  6 MB: w^T bf16 (dead after gemm)
    float* opart = (float*)(ws + ((size_t)24 << 20));   // 16 MB: split-1 partial O (reuses xb/wtb)
    float* ls0   = (float*)(ws + ((size_t)40 << 20));   // 256 KB
    float* ls1   = (float*)(ws + ((size_t)40 << 20) + (256 << 10));

    cvt_fused<<<2048 + 768, 256, 0, stream>>>(x, w, xb, wtb);
    qkv_gemm <<<dim3(SEQ / 128, 3072 / 128), 256, 0, stream>>>(xb, wtb, kq_k, qT, vt);
    attn     <<<1024, 256, 0, stream>>>(kq_k, qT, vt, out, opart, ls0, ls1);
    combine  <<<SEQ * DM / (256 * 8), 256, 0, stream>>>(out, opart, ls0, ls1);
}

// Round 13
// 161.672 us; speedup vs baseline: 2.6579x; 1.0098x over previous
//
#include <hip/hip_runtime.h>
#include <stdint.h>
#include <math.h>

#define SEQ 4096
#define DM  1024
#define NH  16
#define DH  64
#define LOG2E 1.44269504088896341f

typedef short bf16x8 __attribute__((ext_vector_type(8)));
typedef short bf16x4 __attribute__((ext_vector_type(4)));
typedef float f32x4  __attribute__((ext_vector_type(4)));
typedef uint32_t u32x4 __attribute__((ext_vector_type(4)));

typedef const __attribute__((address_space(1))) short* gptr_t;
typedef __attribute__((address_space(3))) short* lptr_t;

__device__ __forceinline__ short f2bf(float f) {
    union { float f; uint32_t u; } x; x.f = f;
    uint32_t r = (x.u + 0x7fffu + ((x.u >> 16) & 1u)) >> 16;
    return (short)r;
}
// pack two f32 -> dword of two truncated bf16 (lo in low half) — plain bit
// ops, fully schedulable (inline-asm variants measured -35%; m240)
__device__ __forceinline__ uint32_t pkbf(float lo, float hi) {
    union { float f; uint32_t u; } a, b; a.f = lo; b.f = hi;
    return (a.u >> 16) | (b.u & 0xffff0000u);
}

__device__ __forceinline__ void load_lds16(const short* g, const short* l) {
    __builtin_amdgcn_global_load_lds((gptr_t)(uintptr_t)g,
                                     (lptr_t)(uint32_t)(uintptr_t)l, 16, 0, 0);
}

// raw workgroup barrier with compiler memory fence (no vmcnt auto-drain)
__device__ __forceinline__ void wgbar() {
    asm volatile("" ::: "memory");
    __builtin_amdgcn_s_barrier();
    asm volatile("" ::: "memory");
}
#define WAITVM(n) asm volatile("s_waitcnt vmcnt(" #n ")" ::: "memory")
#define WAITLGKM(n) do { asm volatile("s_waitcnt lgkmcnt(" #n ")" ::: "memory"); \
                         __builtin_amdgcn_sched_barrier(0); } while (0)
#define DSR(d, a, o) asm volatile("ds_read_b128 %0, %1 offset:" o : "=v"(d) : "v"(a))

// ---- fused prep: blocks [0,2048) convert x fp32->bf16; blocks [2048,2816)
//      transpose w [1024][3072] -> wtb [3072][1024] bf16, Q cols pre-scaled ----
__global__ __launch_bounds__(256) void cvt_fused(const float* __restrict__ x,
                                                 const float* __restrict__ w,
                                                 short* __restrict__ xb,
                                                 short* __restrict__ wtb) {
    __shared__ float T[64][69];
    const int b = blockIdx.x;
    if (b < 2048) {
        const int i = (b * 256 + threadIdx.x) * 8;
        float4 a0 = ((const float4*)(x + i))[0];
        float4 a1 = ((const float4*)(x + i))[1];
        bf16x8 p;
        p[0]=f2bf(a0.x); p[1]=f2bf(a0.y); p[2]=f2bf(a0.z); p[3]=f2bf(a0.w);
        p[4]=f2bf(a1.x); p[5]=f2bf(a1.y); p[6]=f2bf(a1.z); p[7]=f2bf(a1.w);
        *(bf16x8*)(xb + i) = p;
        return;
    }
    const int bb = b - 2048;
    const int n0 = (bb % 48) * 64, k0 = (bb / 48) * 64;
    const int t = threadIdx.x;
    {
        const int kr = t >> 4, nc = (t & 15) * 4;
        #pragma unroll
        for (int i = 0; i < 4; ++i) {
            float4 v = *(const float4*)(w + (size_t)(k0 + kr + i * 16) * 3072 + n0 + nc);
            T[kr + i * 16][nc + 0] = v.x; T[kr + i * 16][nc + 1] = v.y;
            T[kr + i * 16][nc + 2] = v.z; T[kr + i * 16][nc + 3] = v.w;
        }
    }
    __syncthreads();
    const int nr = t >> 4, kc = (t & 15) * 4;
    #pragma unroll
    for (int i = 0; i < 4; ++i) {
        const int n = n0 + nr + i * 16;
        const float sc = (n >= 1024 && n < 2048) ? (LOG2E / 32.0f) : 1.0f;
        short4 o;
        o.x = f2bf(T[kc + 0][nr + i * 16] * sc);
        o.y = f2bf(T[kc + 1][nr + i * 16] * sc);
        o.z = f2bf(T[kc + 2][nr + i * 16] * sc);
        o.w = f2bf(T[kc + 3][nr + i * 16] * sc);
        *(short4*)(wtb + (size_t)n * 1024 + k0 + kc) = o;
    }
}

// ---- QKV GEMM (round-6 proven): 128x128 tile, BK=64, distance-2 prefetch,
//      counted vmcnt(8), raw barriers, XOR-8 swizzled LDS, asm ds_read.
//      Outputs: kq = K|Q [4096][2048] seq-major; vt tau-permuted. ----
__global__ __launch_bounds__(256, 2) void qkv_gemm(const short* __restrict__ xb,
                                                   const short* __restrict__ wtb,
                                                   short* __restrict__ kq,
                                                   short* __restrict__ vt) {
    __shared__ short As[2][8192];
    __shared__ short Bs[2][8192];
    const int col0 = blockIdx.y * 128, row0 = blockIdx.x * 128;
    const int tid = threadIdx.x, w = tid >> 6, lane = tid & 63;
    const int lmod = lane & 15, ldiv = lane >> 4;
    const int wr = (w >> 1) * 64, wc = (w & 1) * 64;

    const int srow = w * 32 + (lane >> 3);
    const int slc  = (lane & 7) ^ ((lane >> 3) & 7);
    const short* gA = xb  + (size_t)(row0 + srow) * 1024 + slc * 8;
    const short* gB = wtb + (size_t)(col0 + srow) * 1024 + slc * 8;
    short* lA = &As[0][0] + w * 2048;
    short* lB = &Bs[0][0] + w * 2048;

    const uint32_t asb = (uint32_t)(uintptr_t)&As[0][0];
    const uint32_t bsb = (uint32_t)(uintptr_t)&Bs[0][0];
    const int xorm = lmod & 7;
    const int rdA = (wr + lmod) * 128 + ((ldiv ^ xorm) << 4);
    const int rdB = (wc + lmod) * 128 + ((ldiv ^ xorm) << 4);

    f32x4 acc[4][4] = {};

    auto stage = [&](int kt, int p) {
        const short* ga = gA + kt * 64;
        const short* gb = gB + kt * 64;
        short* la = lA + p * 8192;
        short* lb = lB + p * 8192;
        #pragma unroll
        for (int q = 0; q < 4; ++q) {
            load_lds16(ga + q * 8192, la + q * 512);
            load_lds16(gb + q * 8192, lb + q * 512);
        }
    };

    stage(0, 0);
    stage(1, 1);
    WAITVM(8);
    wgbar();

    for (int t = 0; t < 16; ++t) {
        const int poff = (t & 1) << 14;
        const int aA0 = (int)asb + poff + rdA, aA1 = aA0 ^ 64;
        const int bA0 = (int)bsb + poff + rdB, bA1 = bA0 ^ 64;
        bf16x8 a0[4], a1[4], b0[4], b1[4];
        DSR(a0[0], aA0, "0");    DSR(a0[1], aA0, "2048");
        DSR(a0[2], aA0, "4096"); DSR(a0[3], aA0, "6144");
        DSR(b0[0], bA0, "0");    DSR(b0[1], bA0, "2048");
        DSR(b0[2], bA0, "4096"); DSR(b0[3], bA0, "6144");
        DSR(a1[0], aA1, "0");    DSR(a1[1], aA1, "2048");
        DSR(a1[2], aA1, "4096"); DSR(a1[3], aA1, "6144");
        DSR(b1[0], bA1, "0");    DSR(b1[1], bA1, "2048");
        DSR(b1[2], bA1, "4096"); DSR(b1[3], bA1, "6144");
        WAITLGKM(8);
        #pragma unroll
        for (int i = 0; i < 4; ++i)
            #pragma unroll
            for (int j = 0; j < 4; ++j)
                acc[i][j] = __builtin_amdgcn_mfma_f32_16x16x32_bf16(a0[i], b0[j], acc[i][j], 0, 0, 0);
        WAITLGKM(0);
        #pragma unroll
        for (int i = 0; i < 4; ++i)
            #pragma unroll
            for (int j = 0; j < 4; ++j)
                acc[i][j] = __builtin_amdgcn_mfma_f32_16x16x32_bf16(a1[i], b1[j], acc[i][j], 0, 0, 0);

        wgbar();
        if (t + 2 < 16) {
            stage(t + 2, t & 1);
            WAITVM(8);
            wgbar();
        } else if (t + 1 < 16) {
            WAITVM(0);
            wgbar();
        }
    }

    if (col0 < 2048) {
        #pragma unroll
        for (int i = 0; i < 4; ++i)
            #pragma unroll
            for (int j = 0; j < 4; ++j)
                #pragma unroll
                for (int r = 0; r < 4; ++r)
                    kq[(size_t)(row0 + wr + i * 16 + ldiv * 4 + r) * 2048
                       + col0 + wc + j * 16 + lmod] = f2bf(acc[i][j][r]);
    } else {
        #pragma unroll
        for (int i = 0; i < 4; ++i) {
            const int ig = row0 + wr + i * 16 + ldiv * 4;
            const int kk = ig & 63;
            // tau: 32a+16b+4c -> 32a+8c+4b
            const int kkp = (kk & 32) | ((kk & 12) << 1) | ((kk & 16) >> 2);
            const int igp = (ig & ~63) | kkp;
            #pragma unroll
            for (int j = 0; j < 4; ++j) {
                const int cg = col0 + wc + j * 16 + lmod - 2048;
                const int h = cg >> 6, d = cg & 63;
                bf16x4 p;
                p[0]=f2bf(acc[i][j][0]); p[1]=f2bf(acc[i][j][1]);
                p[2]=f2bf(acc[i][j][2]); p[3]=f2bf(acc[i][j][3]);
                *(bf16x4*)(vt + (size_t)(h * 64 + d) * SEQ + igp) = p;
            }
        }
    }
}

// ---- flash attention, split-K 2-way, 64-row Q-tiles (v12b).
//  Loop body = round-6 best VERBATIM minus the m-dimension. 2048 blocks;
//  occupancy target 8 blocks/CU comes from ACTUAL resource use (VGPR<=64
//  expected from halved state, 16KB LDS, 256 threads) — launch_bounds kept
//  at the session-proven (256,4); the untested (256,8) bound was the only
//  novel construct in the twice-failed build and is removed. ----
__global__ __launch_bounds__(256, 4) void attn(const short* __restrict__ kq,
                                               const short* __restrict__ vt,
                                               float* __restrict__ o0,
                                               float* __restrict__ o1,
                                               float* __restrict__ ls0,
                                               float* __restrict__ ls1) {
    __shared__ short Ks[64 * 64];
    __shared__ short Vs[64 * 64];

    // 8-band interleaved decode over 64 q-tiles: per-pos j across the 8
    // bands sums to constant work (260 tile-units).
    const int b = blockIdx.x;
    const int band = b >> 8, pos = b & 255, g = pos >> 5;
    const int j = (band & 1) ? (56 - band * 8 + g) : (63 - band * 8 - g);
    const int h = (pos >> 1) & 15, s = pos & 1;

    const int tid = threadIdx.x, w = tid >> 6, lane = tid & 63;
    const int lmod = lane & 15, ldiv = lane >> 4;
    const float slope2 = exp2f(-0.5f * (float)(h + 1)) * LOG2E;

    // staging: wave w stages rows w*16..w*16+15 of both K and V tiles.
    const int sr0 = w * 16 + (lane >> 3), sr1 = sr0 + 8;
    const int sc0 = (lane & 7) ^ (sr0 & 7), sc1 = (lane & 7) ^ (sr1 & 7);

    const int xorm = lmod & 7;                 // read-side swizzle
    const int cxs0 = (ldiv ^ xorm) * 8;        // phys short offset, chunk ldiv
    const int cxs1 = ((4 + ldiv) ^ xorm) * 8;  // phys short offset, chunk 4+ldiv

    const int rowbase = j * 64 + w * 16;       // this wave's 16 q-rows

    // Q fragment (1 m-block x 2 d-chunks) — the MFMA B operand
    bf16x8 qf[2];
    {
        const short* qp = kq + (size_t)(rowbase + lmod) * 2048 + 1024 + h * 64;
        qf[0] = *(const bf16x8*)(qp + ldiv * 8);
        qf[1] = *(const bf16x8*)(qp + 32 + ldiv * 8);
    }
    // swapped layout: lane holds S[k = kt*64 + nt*16 + 4*ldiv + r][q = lmod]
    const int db2 = 4 * ldiv - (rowbase + lmod);
    float pre[4];
    #pragma unroll
    for (int r = 0; r < 4; ++r) pre[r] = slope2 * (float)(db2 + r);

    f32x4 O[4] = {};
    float lsum = 0.0f;
    const int hh = (j + 2) >> 1;               // split point (j=0: s=1 empty)
    const int kt0 = s ? hh : 0;
    const int kt1 = s ? (j + 1) : hh;

    for (int kt = kt0; kt < kt1; ++kt) {
        __syncthreads();   // prev compute done reading Ks/Vs
        {
            const short* kb = kq + (size_t)(kt * 64) * 2048 + h * 64;
            load_lds16(kb + (size_t)sr0 * 2048 + sc0 * 8, Ks + (w * 16) * 64);
            load_lds16(kb + (size_t)sr1 * 2048 + sc1 * 8, Ks + (w * 16 + 8) * 64);
            const short* vb = vt + (size_t)(h * 64) * SEQ + kt * 64;
            load_lds16(vb + (size_t)sr0 * SEQ + sc0 * 8, Vs + (w * 16) * 64);
            load_lds16(vb + (size_t)sr1 * SEQ + sc1 * 8, Vs + (w * 16 + 8) * 64);
        }
        __syncthreads();   // vmcnt drained -> LDS ready

        const bool diag = (kt >= j);
        const int dt = kt * 64;
        const float cb = slope2 * (float)dt;

        #pragma unroll
        for (int ks = 0; ks < 2; ++ks) {       // 32-key chunk for PV
            u32x4 pk;
            #pragma unroll
            for (int j1 = 0; j1 < 2; ++j1) {   // K 16-row block nt = 2ks+j1
                const int nt = ks * 2 + j1;
                const float cn = cb + slope2 * (float)(nt * 16);
                f32x4 s0;
                #pragma unroll
                for (int r = 0; r < 4; ++r) s0[r] = pre[r] + cn;
                const short* krow = Ks + (nt * 16 + lmod) * 64;
                const bf16x8 kf0 = *(const bf16x8*)(krow + cxs0);
                const bf16x8 kf1 = *(const bf16x8*)(krow + cxs1);
                s0 = __builtin_amdgcn_mfma_f32_16x16x32_bf16(kf0, qf[0], s0, 0, 0, 0);
                s0 = __builtin_amdgcn_mfma_f32_16x16x32_bf16(kf1, qf[1], s0, 0, 0, 0);

                float p0[4];
                if (diag) {
                    #pragma unroll
                    for (int r = 0; r < 4; ++r) {
                        float v0 = s0[r];
                        if (dt + nt * 16 + r + db2 > 0) v0 = -1e30f;
                        p0[r] = __builtin_amdgcn_exp2f(v0);
                    }
                } else {
                    #pragma unroll
                    for (int r = 0; r < 4; ++r)
                        p0[r] = __builtin_amdgcn_exp2f(s0[r]);
                }
                lsum += (p0[0] + p0[1]) + (p0[2] + p0[3]);
                pk[j1 * 2]     = pkbf(p0[0], p0[1]);
                pk[j1 * 2 + 1] = pkbf(p0[2], p0[3]);
            }
            const bf16x8 pa = __builtin_bit_cast(bf16x8, pk);
            const int cxo = ks ? cxs1 : cxs0;
            #pragma unroll
            for (int nt2 = 0; nt2 < 4; ++nt2) {
                const bf16x8 vf = *(const bf16x8*)(Vs + (nt2 * 16 + lmod) * 64 + cxo);
                O[nt2] = __builtin_amdgcn_mfma_f32_16x16x32_bf16(pa, vf, O[nt2], 0, 0, 0);
            }
        }
    }

    // row sum: lane holds partial for q = lmod; reduce across ldiv groups
    {
        float v = lsum;
        v += __shfl_xor(v, 16);
        v += __shfl_xor(v, 32);
        lsum = v;
    }

    float* ob = s ? o1 : o0;
    float* lb = s ? ls1 : ls0;
    const int i0 = rowbase + ldiv * 4;
    #pragma unroll
    for (int nt2 = 0; nt2 < 4; ++nt2)
        #pragma unroll
        for (int r = 0; r < 4; ++r)
            ob[(size_t)(i0 + r) * DM + h * 64 + nt2 * 16 + lmod] = O[nt2][r];
    if (ldiv == 0)
        lb[h * SEQ + rowbase + lmod] = lsum;
}

// ---- combine: out = (O0 + O1) / (l0 + l1) ----
__global__ __launch_bounds__(256) void combine(float* __restrict__ out,
                                               const float* __restrict__ opart,
                                               const float* __restrict__ ls0,
                                               const float* __restrict__ ls1) {
    const int i8 = (blockIdx.x * 256 + threadIdx.x) * 8;
    const int row = i8 >> 10, col = i8 & 1023, h = col >> 6;
    const float l = ls0[h * SEQ + row] + ls1[h * SEQ + row];
    const float rc = 1.0f / l;
    float4 a0 = *(const float4*)(out + i8);
    float4 a1 = *(const float4*)(out + i8 + 4);
    float4 b0 = *(const float4*)(opart + i8);
    float4 b1 = *(const float4*)(opart + i8 + 4);
    float4 c0, c1;
    c0.x = (a0.x + b0.x) * rc; c0.y = (a0.y + b0.y) * rc;
    c0.z = (a0.z + b0.z) * rc; c0.w = (a0.w + b0.w) * rc;
    c1.x = (a1.x + b1.x) * rc; c1.y = (a1.y + b1.y) * rc;
    c1.z = (a1.z + b1.z) * rc; c1.w = (a1.w + b1.w) * rc;
    *(float4*)(out + i8) = c0;
    *(float4*)(out + i8 + 4) = c1;
}

extern "C" void kernel_launch(void* const* d_in, const int* in_sizes, int n_in,
                              void* d_out, int out_size, void* d_ws, size_t ws_size,
                              hipStream_t stream) {
    const float* x = (const float*)d_in[0];   // [1,4096,1024] fp32
    const float* w = (const float*)d_in[1];   // [1024,3072] fp32
    float* out = (float*)d_out;

    char* ws = (char*)d_ws;
    short* kq    = (short*)(ws);                        // 16 MB: K|Q [4096][2048]
    short* vt    = (short*)(ws + ((size_t)16 << 20));   //  8 MB: V^T [16][64][4096] (tau-permuted keys)
    short* xb    = (short*)(ws + ((size_t)24 << 20));   //  8 MB: x bf16 (dead after gemm)
    short* wtb   = (short*)(ws + ((size_t)32 << 20));   //  6 MB: w^T bf16 (dead after gemm)
    float* opart = (float*)(ws + ((size_t)24 << 20));   // 16 MB: split-1 partial O (reuses xb/wtb)
    float* ls0   = (float*)(ws + ((size_t)40 << 20));   // 256 KB
    float* ls1   = (float*)(ws + ((size_t)40 << 20) + (256 << 10));

    cvt_fused<<<2048 + 768, 256, 0, stream>>>(x, w, xb, wtb);
    qkv_gemm <<<dim3(SEQ / 128, 3072 / 128), 256, 0, stream>>>(xb, wtb, kq, vt);
    attn     <<<2048, 256, 0, stream>>>(kq, vt, out, opart, ls0, ls1);
    combine  <<<SEQ * DM / (256 * 8), 256, 0, stream>>>(out, opart, ls0, ls1);
}

// Round 14
// 160.927 us; speedup vs baseline: 2.6702x; 1.0046x over previous
//
#include <hip/hip_runtime.h>
#include <stdint.h>
#include <math.h>

#define SEQ 4096
#define DM  1024
#define NH  16
#define DH  64
#define LOG2E 1.44269504088896341f

typedef short bf16x8 __attribute__((ext_vector_type(8)));
typedef short bf16x4 __attribute__((ext_vector_type(4)));
typedef float f32x4  __attribute__((ext_vector_type(4)));
typedef uint32_t u32x4 __attribute__((ext_vector_type(4)));

typedef const __attribute__((address_space(1))) short* gptr_t;
typedef __attribute__((address_space(3))) short* lptr_t;

__device__ __forceinline__ short f2bf(float f) {
    union { float f; uint32_t u; } x; x.f = f;
    uint32_t r = (x.u + 0x7fffu + ((x.u >> 16) & 1u)) >> 16;
    return (short)r;
}
// pack two f32 -> dword of two truncated bf16 (lo in low half):
// ONE v_perm_b32 (intrinsic, scheduler-visible — not opaque asm).
// Same truncation semantics as the previous 3-op bit version.
__device__ __forceinline__ uint32_t pkbf(float lo, float hi) {
    union { float f; uint32_t u; } a, b; a.f = lo; b.f = hi;
    return __builtin_amdgcn_perm(b.u, a.u, 0x07060302u);
}

__device__ __forceinline__ void load_lds16(const short* g, const short* l) {
    __builtin_amdgcn_global_load_lds((gptr_t)(uintptr_t)g,
                                     (lptr_t)(uint32_t)(uintptr_t)l, 16, 0, 0);
}

// raw workgroup barrier with compiler memory fence (no vmcnt auto-drain)
__device__ __forceinline__ void wgbar() {
    asm volatile("" ::: "memory");
    __builtin_amdgcn_s_barrier();
    asm volatile("" ::: "memory");
}
#define WAITVM(n) asm volatile("s_waitcnt vmcnt(" #n ")" ::: "memory")
#define WAITLGKM(n) do { asm volatile("s_waitcnt lgkmcnt(" #n ")" ::: "memory"); \
                         __builtin_amdgcn_sched_barrier(0); } while (0)
#define DSR(d, a, o) asm volatile("ds_read_b128 %0, %1 offset:" o : "=v"(d) : "v"(a))

// ---- fused prep: blocks [0,2048) convert x fp32->bf16; blocks [2048,2816)
//      transpose w [1024][3072] -> wtb [3072][1024] bf16, Q cols pre-scaled ----
__global__ __launch_bounds__(256) void cvt_fused(const float* __restrict__ x,
                                                 const float* __restrict__ w,
                                                 short* __restrict__ xb,
                                                 short* __restrict__ wtb) {
    __shared__ float T[64][69];
    const int b = blockIdx.x;
    if (b < 2048) {
        const int i = (b * 256 + threadIdx.x) * 8;
        float4 a0 = ((const float4*)(x + i))[0];
        float4 a1 = ((const float4*)(x + i))[1];
        bf16x8 p;
        p[0]=f2bf(a0.x); p[1]=f2bf(a0.y); p[2]=f2bf(a0.z); p[3]=f2bf(a0.w);
        p[4]=f2bf(a1.x); p[5]=f2bf(a1.y); p[6]=f2bf(a1.z); p[7]=f2bf(a1.w);
        *(bf16x8*)(xb + i) = p;
        return;
    }
    const int bb = b - 2048;
    const int n0 = (bb % 48) * 64, k0 = (bb / 48) * 64;
    const int t = threadIdx.x;
    {
        const int kr = t >> 4, nc = (t & 15) * 4;
        #pragma unroll
        for (int i = 0; i < 4; ++i) {
            float4 v = *(const float4*)(w + (size_t)(k0 + kr + i * 16) * 3072 + n0 + nc);
            T[kr + i * 16][nc + 0] = v.x; T[kr + i * 16][nc + 1] = v.y;
            T[kr + i * 16][nc + 2] = v.z; T[kr + i * 16][nc + 3] = v.w;
        }
    }
    __syncthreads();
    const int nr = t >> 4, kc = (t & 15) * 4;
    #pragma unroll
    for (int i = 0; i < 4; ++i) {
        const int n = n0 + nr + i * 16;
        const float sc = (n >= 1024 && n < 2048) ? (LOG2E / 32.0f) : 1.0f;
        short4 o;
        o.x = f2bf(T[kc + 0][nr + i * 16] * sc);
        o.y = f2bf(T[kc + 1][nr + i * 16] * sc);
        o.z = f2bf(T[kc + 2][nr + i * 16] * sc);
        o.w = f2bf(T[kc + 3][nr + i * 16] * sc);
        *(short4*)(wtb + (size_t)n * 1024 + k0 + kc) = o;
    }
}

// ---- QKV GEMM (round-6 proven): 128x128 tile, BK=64, distance-2 prefetch,
//      counted vmcnt(8), raw barriers, XOR-8 swizzled LDS, asm ds_read.
//      Outputs: kq = K|Q [4096][2048] seq-major; vt tau-permuted. ----
__global__ __launch_bounds__(256, 2) void qkv_gemm(const short* __restrict__ xb,
                                                   const short* __restrict__ wtb,
                                                   short* __restrict__ kq,
                                                   short* __restrict__ vt) {
    __shared__ short As[2][8192];
    __shared__ short Bs[2][8192];
    const int col0 = blockIdx.y * 128, row0 = blockIdx.x * 128;
    const int tid = threadIdx.x, w = tid >> 6, lane = tid & 63;
    const int lmod = lane & 15, ldiv = lane >> 4;
    const int wr = (w >> 1) * 64, wc = (w & 1) * 64;

    const int srow = w * 32 + (lane >> 3);
    const int slc  = (lane & 7) ^ ((lane >> 3) & 7);
    const short* gA = xb  + (size_t)(row0 + srow) * 1024 + slc * 8;
    const short* gB = wtb + (size_t)(col0 + srow) * 1024 + slc * 8;
    short* lA = &As[0][0] + w * 2048;
    short* lB = &Bs[0][0] + w * 2048;

    const uint32_t asb = (uint32_t)(uintptr_t)&As[0][0];
    const uint32_t bsb = (uint32_t)(uintptr_t)&Bs[0][0];
    const int xorm = lmod & 7;
    const int rdA = (wr + lmod) * 128 + ((ldiv ^ xorm) << 4);
    const int rdB = (wc + lmod) * 128 + ((ldiv ^ xorm) << 4);

    f32x4 acc[4][4] = {};

    auto stage = [&](int kt, int p) {
        const short* ga = gA + kt * 64;
        const short* gb = gB + kt * 64;
        short* la = lA + p * 8192;
        short* lb = lB + p * 8192;
        #pragma unroll
        for (int q = 0; q < 4; ++q) {
            load_lds16(ga + q * 8192, la + q * 512);
            load_lds16(gb + q * 8192, lb + q * 512);
        }
    };

    stage(0, 0);
    stage(1, 1);
    WAITVM(8);
    wgbar();

    for (int t = 0; t < 16; ++t) {
        const int poff = (t & 1) << 14;
        const int aA0 = (int)asb + poff + rdA, aA1 = aA0 ^ 64;
        const int bA0 = (int)bsb + poff + rdB, bA1 = bA0 ^ 64;
        bf16x8 a0[4], a1[4], b0[4], b1[4];
        DSR(a0[0], aA0, "0");    DSR(a0[1], aA0, "2048");
        DSR(a0[2], aA0, "4096"); DSR(a0[3], aA0, "6144");
        DSR(b0[0], bA0, "0");    DSR(b0[1], bA0, "2048");
        DSR(b0[2], bA0, "4096"); DSR(b0[3], bA0, "6144");
        DSR(a1[0], aA1, "0");    DSR(a1[1], aA1, "2048");
        DSR(a1[2], aA1, "4096"); DSR(a1[3], aA1, "6144");
        DSR(b1[0], bA1, "0");    DSR(b1[1], bA1, "2048");
        DSR(b1[2], bA1, "4096"); DSR(b1[3], bA1, "6144");
        WAITLGKM(8);
        #pragma unroll
        for (int i = 0; i < 4; ++i)
            #pragma unroll
            for (int j = 0; j < 4; ++j)
                acc[i][j] = __builtin_amdgcn_mfma_f32_16x16x32_bf16(a0[i], b0[j], acc[i][j], 0, 0, 0);
        WAITLGKM(0);
        #pragma unroll
        for (int i = 0; i < 4; ++i)
            #pragma unroll
            for (int j = 0; j < 4; ++j)
                acc[i][j] = __builtin_amdgcn_mfma_f32_16x16x32_bf16(a1[i], b1[j], acc[i][j], 0, 0, 0);

        wgbar();
        if (t + 2 < 16) {
            stage(t + 2, t & 1);
            WAITVM(8);
            wgbar();
        } else if (t + 1 < 16) {
            WAITVM(0);
            wgbar();
        }
    }

    if (col0 < 2048) {
        #pragma unroll
        for (int i = 0; i < 4; ++i)
            #pragma unroll
            for (int j = 0; j < 4; ++j)
                #pragma unroll
                for (int r = 0; r < 4; ++r)
                    kq[(size_t)(row0 + wr + i * 16 + ldiv * 4 + r) * 2048
                       + col0 + wc + j * 16 + lmod] = f2bf(acc[i][j][r]);
    } else {
        #pragma unroll
        for (int i = 0; i < 4; ++i) {
            const int ig = row0 + wr + i * 16 + ldiv * 4;
            const int kk = ig & 63;
            // tau: 32a+16b+4c -> 32a+8c+4b
            const int kkp = (kk & 32) | ((kk & 12) << 1) | ((kk & 16) >> 2);
            const int igp = (ig & ~63) | kkp;
            #pragma unroll
            for (int j = 0; j < 4; ++j) {
                const int cg = col0 + wc + j * 16 + lmod - 2048;
                const int h = cg >> 6, d = cg & 63;
                bf16x4 p;
                p[0]=f2bf(acc[i][j][0]); p[1]=f2bf(acc[i][j][1]);
                p[2]=f2bf(acc[i][j][2]); p[3]=f2bf(acc[i][j][3]);
                *(bf16x4*)(vt + (size_t)(h * 64 + d) * SEQ + igp) = p;
            }
        }
    }
}

// ---- flash attention, split-K 2-way, 64-row Q-tiles (v13).
//  = v12b (proven schedule: single-buffer LDS, 2-barrier staging, zero asm
//  in the loop) + two VALU cuts:
//   1. pkbf via v_perm_b32 intrinsic (1 op vs 3, same truncation)
//   2. lsum via MFMA ones-fragment: lsacc = mfma(pa, ones, lsacc) gives
//      per-q row sums on the matrix pipe; kills 12 adds/tile + end shuffles.
//      Denominator now sums the same truncated-bf16 P as the numerator. ----
__global__ __launch_bounds__(256, 4) void attn(const short* __restrict__ kq,
                                               const short* __restrict__ vt,
                                               float* __restrict__ o0,
                                               float* __restrict__ o1,
                                               float* __restrict__ ls0,
                                               float* __restrict__ ls1) {
    __shared__ short Ks[64 * 64];
    __shared__ short Vs[64 * 64];

    // 8-band interleaved decode over 64 q-tiles: per-pos j across the 8
    // bands sums to constant work (260 tile-units).
    const int b = blockIdx.x;
    const int band = b >> 8, pos = b & 255, g = pos >> 5;
    const int j = (band & 1) ? (56 - band * 8 + g) : (63 - band * 8 - g);
    const int h = (pos >> 1) & 15, s = pos & 1;

    const int tid = threadIdx.x, w = tid >> 6, lane = tid & 63;
    const int lmod = lane & 15, ldiv = lane >> 4;
    const float slope2 = exp2f(-0.5f * (float)(h + 1)) * LOG2E;

    // staging: wave w stages rows w*16..w*16+15 of both K and V tiles.
    const int sr0 = w * 16 + (lane >> 3), sr1 = sr0 + 8;
    const int sc0 = (lane & 7) ^ (sr0 & 7), sc1 = (lane & 7) ^ (sr1 & 7);

    const int xorm = lmod & 7;                 // read-side swizzle
    const int cxs0 = (ldiv ^ xorm) * 8;        // phys short offset, chunk ldiv
    const int cxs1 = ((4 + ldiv) ^ xorm) * 8;  // phys short offset, chunk 4+ldiv

    const int rowbase = j * 64 + w * 16;       // this wave's 16 q-rows

    // Q fragment (1 m-block x 2 d-chunks) — the MFMA B operand
    bf16x8 qf[2];
    {
        const short* qp = kq + (size_t)(rowbase + lmod) * 2048 + 1024 + h * 64;
        qf[0] = *(const bf16x8*)(qp + ldiv * 8);
        qf[1] = *(const bf16x8*)(qp + 32 + ldiv * 8);
    }
    // ones fragment for the lsum MFMA (bf16 1.0 = 0x3F80)
    bf16x8 ones;
    #pragma unroll
    for (int e = 0; e < 8; ++e) ones[e] = (short)0x3F80;

    // swapped layout: lane holds S[k = kt*64 + nt*16 + 4*ldiv + r][q = lmod]
    const int db2 = 4 * ldiv - (rowbase + lmod);
    float pre[4];
    #pragma unroll
    for (int r = 0; r < 4; ++r) pre[r] = slope2 * (float)(db2 + r);

    f32x4 O[4] = {};
    f32x4 lsacc = {};   // lane: lsacc[r] = rowsum for q_local = 4*ldiv + r
    const int hh = (j + 2) >> 1;               // split point (j=0: s=1 empty)
    const int kt0 = s ? hh : 0;
    const int kt1 = s ? (j + 1) : hh;

    for (int kt = kt0; kt < kt1; ++kt) {
        __syncthreads();   // prev compute done reading Ks/Vs
        {
            const short* kb = kq + (size_t)(kt * 64) * 2048 + h * 64;
            load_lds16(kb + (size_t)sr0 * 2048 + sc0 * 8, Ks + (w * 16) * 64);
            load_lds16(kb + (size_t)sr1 * 2048 + sc1 * 8, Ks + (w * 16 + 8) * 64);
            const short* vb = vt + (size_t)(h * 64) * SEQ + kt * 64;
            load_lds16(vb + (size_t)sr0 * SEQ + sc0 * 8, Vs + (w * 16) * 64);
            load_lds16(vb + (size_t)sr1 * SEQ + sc1 * 8, Vs + (w * 16 + 8) * 64);
        }
        __syncthreads();   // vmcnt drained -> LDS ready

        const bool diag = (kt >= j);
        const int dt = kt * 64;
        const float cb = slope2 * (float)dt;

        #pragma unroll
        for (int ks = 0; ks < 2; ++ks) {       // 32-key chunk for PV
            u32x4 pk;
            #pragma unroll
            for (int j1 = 0; j1 < 2; ++j1) {   // K 16-row block nt = 2ks+j1
                const int nt = ks * 2 + j1;
                const float cn = cb + slope2 * (float)(nt * 16);
                f32x4 s0;
                #pragma unroll
                for (int r = 0; r < 4; ++r) s0[r] = pre[r] + cn;
                const short* krow = Ks + (nt * 16 + lmod) * 64;
                const bf16x8 kf0 = *(const bf16x8*)(krow + cxs0);
                const bf16x8 kf1 = *(const bf16x8*)(krow + cxs1);
                s0 = __builtin_amdgcn_mfma_f32_16x16x32_bf16(kf0, qf[0], s0, 0, 0, 0);
                s0 = __builtin_amdgcn_mfma_f32_16x16x32_bf16(kf1, qf[1], s0, 0, 0, 0);

                float p0[4];
                if (diag) {
                    #pragma unroll
                    for (int r = 0; r < 4; ++r) {
                        float v0 = s0[r];
                        if (dt + nt * 16 + r + db2 > 0) v0 = -1e30f;
                        p0[r] = __builtin_amdgcn_exp2f(v0);
                    }
                } else {
                    #pragma unroll
                    for (int r = 0; r < 4; ++r)
                        p0[r] = __builtin_amdgcn_exp2f(s0[r]);
                }
                pk[j1 * 2]     = pkbf(p0[0], p0[1]);
                pk[j1 * 2 + 1] = pkbf(p0[2], p0[3]);
            }
            const bf16x8 pa = __builtin_bit_cast(bf16x8, pk);
            const int cxo = ks ? cxs1 : cxs0;
            lsacc = __builtin_amdgcn_mfma_f32_16x16x32_bf16(pa, ones, lsacc, 0, 0, 0);
            #pragma unroll
            for (int nt2 = 0; nt2 < 4; ++nt2) {
                const bf16x8 vf = *(const bf16x8*)(Vs + (nt2 * 16 + lmod) * 64 + cxo);
                O[nt2] = __builtin_amdgcn_mfma_f32_16x16x32_bf16(pa, vf, O[nt2], 0, 0, 0);
            }
        }
    }

    float* ob = s ? o1 : o0;
    float* lb = s ? ls1 : ls0;
    const int i0 = rowbase + ldiv * 4;
    #pragma unroll
    for (int nt2 = 0; nt2 < 4; ++nt2)
        #pragma unroll
        for (int r = 0; r < 4; ++r)
            ob[(size_t)(i0 + r) * DM + h * 64 + nt2 * 16 + lmod] = O[nt2][r];
    // lsacc columns are identical; publish from lmod==0 (rows 4*ldiv+r)
    if (lmod == 0) {
        #pragma unroll
        for (int r = 0; r < 4; ++r)
            lb[h * SEQ + i0 + r] = lsacc[r];
    }
}

// ---- combine: out = (O0 + O1) / (l0 + l1) ----
__global__ __launch_bounds__(256) void combine(float* __restrict__ out,
                                               const float* __restrict__ opart,
                                               const float* __restrict__ ls0,
                                               const float* __restrict__ ls1) {
    const int i8 = (blockIdx.x * 256 + threadIdx.x) * 8;
    const int row = i8 >> 10, col = i8 & 1023, h = col >> 6;
    const float l = ls0[h * SEQ + row] + ls1[h * SEQ + row];
    const float rc = 1.0f / l;
    float4 a0 = *(const float4*)(out + i8);
    float4 a1 = *(const float4*)(out + i8 + 4);
    float4 b0 = *(const float4*)(opart + i8);
    float4 b1 = *(const float4*)(opart + i8 + 4);
    float4 c0, c1;
    c0.x = (a0.x + b0.x) * rc; c0.y = (a0.y + b0.y) * rc;
    c0.z = (a0.z + b0.z) * rc; c0.w = (a0.w + b0.w) * rc;
    c1.x = (a1.x + b1.x) * rc; c1.y = (a1.y + b1.y) * rc;
    c1.z = (a1.z + b1.z) * rc; c1.w = (a1.w + b1.w) * rc;
    *(float4*)(out + i8) = c0;
    *(float4*)(out + i8 + 4) = c1;
}

extern "C" void kernel_launch(void* const* d_in, const int* in_sizes, int n_in,
                              void* d_out, int out_size, void* d_ws, size_t ws_size,
                              hipStream_t stream) {
    const float* x = (const float*)d_in[0];   // [1,4096,1024] fp32
    const float* w = (const float*)d_in[1];   // [1024,3072] fp32
    float* out = (float*)d_out;

    char* ws = (char*)d_ws;
    short* kq    = (short*)(ws);                        // 16 MB: K|Q [4096][2048]
    short* vt    = (short*)(ws + ((size_t)16 << 20));   //  8 MB: V^T [16][64][4096] (tau-permuted keys)
    short* xb    = (short*)(ws + ((size_t)24 << 20));   //  8 MB: x bf16 (dead after gemm)
    short* wtb   = (short*)(ws + ((size_t)32 << 20));   //  6 MB: w^T bf16 (dead after gemm)
    float* opart = (float*)(ws + ((size_t)24 << 20));   // 16 MB: split-1 partial O (reuses xb/wtb)
    float* ls0   = (float*)(ws + ((size_t)40 << 20));   // 256 KB
    float* ls1   = (float*)(ws + ((size_t)40 << 20) + (256 << 10));

    cvt_fused<<<2048 + 768, 256, 0, stream>>>(x, w, xb, wtb);
    qkv_gemm <<<dim3(SEQ / 128, 3072 / 128), 256, 0, stream>>>(xb, wtb, kq, vt);
    attn     <<<2048, 256, 0, stream>>>(kq, vt, out, opart, ls0, ls1);
    combine  <<<SEQ * DM / (256 * 8), 256, 0, stream>>>(out, opart, ls0, ls1);
}